// Round 8
// baseline (1698.915 us; speedup 1.0000x reference)
//
#include <hip/hip_runtime.h>
#include <math.h>

#define HH 256
#define GG 1024
#define LL 48
#define NNODES 49152   // G*L
#define NEDGES 98304   // 2*N
#define SB 256.0f      // weight-side scale 2^8
#define DSB 0.00390625f // 2^-8

typedef _Float16 f16;
typedef __attribute__((ext_vector_type(8))) _Float16 f16x8;
typedef __attribute__((ext_vector_type(4))) float f32x4;

#define MFMA16(a, b, c) __builtin_amdgcn_mfma_f32_16x16x32_f16(a, b, c, 0, 0, 0)

__device__ inline float sc_from_max(float m) {
    if (!(m > 0.f)) return 1.0f;
    return ldexpf(1.0f, 13 - ilogbf(m));   // m*sc in [2^13, 2^14)
}

// ---------------------------------------------------------------------------
// CSR build (verified round 2-6)
// ---------------------------------------------------------------------------
__global__ void csr_count(const int* __restrict__ row, int* __restrict__ counts)
{
    int e = blockIdx.x * 256 + threadIdx.x;
    if (e < NEDGES) atomicAdd(&counts[row[e]], 1);
}

__global__ __launch_bounds__(1024) void scan_offsets(const int* __restrict__ counts,
                                                     int* __restrict__ offsets)
{
    __shared__ int tsum[1024];
    const int tid = threadIdx.x;
    const int base = tid * 48;
    int s = 0;
    for (int i = 0; i < 48; i++) s += counts[base + i];
    tsum[tid] = s;
    __syncthreads();
    for (int off = 1; off < 1024; off <<= 1) {
        int v = (tid >= off) ? tsum[tid - off] : 0;
        __syncthreads();
        tsum[tid] += v;
        __syncthreads();
    }
    int run = (tid == 0) ? 0 : tsum[tid - 1];
    for (int i = 0; i < 48; i++) { offsets[base + i] = run; run += counts[base + i]; }
    if (tid == 1023) offsets[NNODES] = run;
}

__global__ void csr_fill(const int* __restrict__ row, const int* __restrict__ offsets,
                         int* __restrict__ cursor, int* __restrict__ elist)
{
    int e = blockIdx.x * 256 + threadIdx.x;
    if (e < NEDGES) {
        int r = row[e];
        int p = atomicAdd(&cursor[r], 1);
        elist[offsets[r] + p] = e;
    }
}

__global__ void prep_graphs(const int* __restrict__ batch, int* __restrict__ starts,
                            int* __restrict__ gcnt)
{
    int i = blockIdx.x * 256 + threadIdx.x;
    if (i < NNODES) {
        int b = batch[i];
        atomicAdd(&gcnt[b], 1);
        if (i == 0 || batch[i - 1] != b) starts[b] = i;
    }
}

__global__ void rowscale(const float* __restrict__ A, int K, float* __restrict__ sc)
{
    int m = blockIdx.x, ln = threadIdx.x;
    float v = 0.f;
    for (int k = ln; k < K; k += 64) v = fmaxf(v, fabsf(A[(size_t)m * K + k]));
    for (int s = 32; s; s >>= 1) v = fmaxf(v, __shfl_xor(v, s));
    if (ln == 0) sc[m] = sc_from_max(v);
}

// weight prep: W[K][256] f32 -> blocked transposed f16 hi/lo [kblk][256][32], x2^8
__global__ void prep_wT(const float* __restrict__ Wsrc, f16* __restrict__ oH,
                        f16* __restrict__ oL)
{
    int idx = blockIdx.x * 256 + threadIdx.x;
    int k = idx >> 8, n = idx & 255;
    float v = Wsrc[(size_t)k * 256 + n] * SB;
    f16 h = (f16)v;
    size_t o = ((size_t)(k >> 5) * 256 + n) * 32 + (k & 31);
    oH[o] = h;
    oL[o] = (f16)(v - (float)h);
}

// GRU weight prep (round-6 version): cols interleaved 4*jj+s; [d][kblk][1024][32] hi/lo
__global__ void prep_gruW(const float* __restrict__ w_ih, const float* __restrict__ w_hh,
                          const float* __restrict__ b_ih, const float* __restrict__ b_hh,
                          f16* __restrict__ BgH, f16* __restrict__ BgL,
                          float* __restrict__ bias4)
{
    int idx = blockIdx.x * 256 + threadIdx.x;   // 2*512*1024
    int d = idx >> 19;
    int rem = idx & 524287;
    int k = rem >> 10;
    int col = rem & 1023;
    int jj = col >> 2, s = col & 3;
    const float* Wi = w_ih + (size_t)d * 768 * 256;
    const float* Wh = w_hh + (size_t)d * 768 * 256;
    float v;
    if (s == 0)      v = (k < 256) ? Wi[(size_t)jj * 256 + k]         : Wh[(size_t)jj * 256 + (k - 256)];
    else if (s == 1) v = (k < 256) ? Wi[(size_t)(256 + jj) * 256 + k] : Wh[(size_t)(256 + jj) * 256 + (k - 256)];
    else if (s == 2) v = (k < 256) ? Wi[(size_t)(512 + jj) * 256 + k] : 0.f;
    else             v = (k < 256) ? 0.f : Wh[(size_t)(512 + jj) * 256 + (k - 256)];
    v *= SB;
    f16 h = (f16)v;
    size_t o = ((size_t)(d * 16 + (k >> 5)) * 1024 + col) * 32 + (k & 31);
    BgH[o] = h;
    BgL[o] = (f16)(v - (float)h);
    if (k == 0) {
        const float* bi = b_ih + d * 768;
        const float* bh = b_hh + d * 768;
        float bv;
        if (s == 0)      bv = bi[jj] + bh[jj];
        else if (s == 1) bv = bi[256 + jj] + bh[256 + jj];
        else if (s == 2) bv = bi[512 + jj];
        else             bv = bh[512 + jj];
        bias4[d * 1024 + col] = bv;
    }
}

// booster + per-node scale (verified round 3-6)
__global__ void booster(const float* __restrict__ hb_lo, const float* __restrict__ hb_hi,
                        const float* __restrict__ atom_in, float* __restrict__ out,
                        const int* __restrict__ offsets, const int* __restrict__ elist,
                        float* __restrict__ scOut)
{
    int n = blockIdx.x, c = threadIdx.x;
    int b0 = offsets[n], b1 = offsets[n + 1];
    float s = 0.f, m = 0.f;
    for (int p = b0; p < b1; p++) {
        int e = elist[p];
        const float* hb = (e < NNODES) ? (hb_lo + (size_t)e * HH)
                                       : (hb_hi + (size_t)(e - NNODES) * HH);
        float v = hb[c];
        s += v;
        m = fmaxf(m, v);
    }
    float o = atom_in[(size_t)n * HH + c] + s * m;
    out[(size_t)n * HH + c] = o;
    float v = fabsf(o);
    for (int t = 32; t; t >>= 1) v = fmaxf(v, __shfl_xor(v, t));
    __shared__ float wm[4];
    if ((c & 63) == 0) wm[c >> 6] = v;
    __syncthreads();
    if (c == 0)
        scOut[n] = sc_from_max(fmaxf(fmaxf(wm[0], wm[1]), fmaxf(wm[2], wm[3])));
}

__global__ void h0_init(const float* __restrict__ h, const int* __restrict__ starts,
                        const int* __restrict__ gcnt, float* __restrict__ hid0,
                        float* __restrict__ scG)
{
    int g = blockIdx.x, c = threadIdx.x;
    int st = starts[g], cn = gcnt[g];
    float m = -INFINITY, am = 0.f;
    for (int i = 0; i < cn; i++) {
        float v = h[(size_t)(st + i) * HH + c];
        m = fmaxf(m, v);
        am = fmaxf(am, fabsf(v));
    }
    if (cn == 0) m = 0.f;
    hid0[(size_t)g * HH + c] = m;
    hid0[(size_t)GG * HH + (size_t)g * HH + c] = m;
    for (int t = 32; t; t >>= 1) am = fmaxf(am, __shfl_xor(am, t));
    __shared__ float wm[4];
    if ((c & 63) == 0) wm[c >> 6] = am;
    __syncthreads();
    if (c == 0) {
        float M = fmaxf(fmaxf(fmaxf(wm[0], wm[1]), fmaxf(wm[2], wm[3])) + 0.07f, 1.0f);
        scG[g] = sc_from_max(M);
    }
}

// msgP[l][g][k] = relu(h[starts[g]+l][k] + gru_bias[k]) (0 for invalid l)
__global__ void build_msgP(const float* __restrict__ h, const float* __restrict__ gbias,
                           const int* __restrict__ starts, const int* __restrict__ gcnt,
                           float* __restrict__ msgP)
{
    int l = blockIdx.x, g = blockIdx.y, k = threadIdx.x;
    float v = 0.f;
    if (l < gcnt[g]) {
        int node = starts[g] + l;
        v = fmaxf(h[(size_t)node * HH + k] + gbias[k], 0.f);
    }
    msgP[((size_t)l * GG + g) * HH + k] = v;
}

// ---------------------------------------------------------------------------
// A-tile element loaders (8 consecutive k of one row)
// ---------------------------------------------------------------------------
template<int MODE>
__device__ __forceinline__ void gemmLoadA(const float* __restrict__ A,
    const float* __restrict__ S0, const float* __restrict__ S1,
    const float* __restrict__ S2, int rI, int cI, int row, int K, int k,
    float va[8])
{
    if constexpr (MODE == 0) {
        const float* p = A + (size_t)row * K + k;
        float4 v0 = *(const float4*)p, v1 = *(const float4*)(p + 4);
        va[0]=v0.x; va[1]=v0.y; va[2]=v0.z; va[3]=v0.w;
        va[4]=v1.x; va[5]=v1.y; va[6]=v1.z; va[7]=v1.w;
    } else if constexpr (MODE == 1) {
        const float* pa = S0 + (size_t)rI * HH + k;
        const float* pb = S1 + (size_t)cI * HH + k;
        float4 a0 = *(const float4*)pa, a1 = *(const float4*)(pa + 4);
        float4 b0 = *(const float4*)pb, b1 = *(const float4*)(pb + 4);
        va[0]=a0.x-b0.x; va[1]=a0.y-b0.y; va[2]=a0.z-b0.z; va[3]=a0.w-b0.w;
        va[4]=a1.x-b1.x; va[5]=a1.y-b1.y; va[6]=a1.z-b1.z; va[7]=a1.w-b1.w;
    } else if constexpr (MODE == 2) {
        const float* S = (k < 256) ? S0 : ((k < 512) ? S1 : S2);
        const float* p = S + (size_t)row * HH + (k & 255);
        float4 v0 = *(const float4*)p, v1 = *(const float4*)(p + 4);
        va[0]=v0.x; va[1]=v0.y; va[2]=v0.z; va[3]=v0.w;
        va[4]=v1.x; va[5]=v1.y; va[6]=v1.z; va[7]=v1.w;
    } else {
        const float* S = (k < 256) ? S0 : S1;
        const float* p = S + (size_t)row * HH + (k & 255);
        float4 v0 = *(const float4*)p, v1 = *(const float4*)(p + 4);
        va[0]=v0.x; va[1]=v0.y; va[2]=v0.z; va[3]=v0.w;
        va[4]=v1.x; va[5]=v1.y; va[6]=v1.z; va[7]=v1.w;
    }
}

// ---------------------------------------------------------------------------
// f16 split MFMA GEMM v2: A staged in LDS (hi/lo); B fragments loaded DIRECTLY
// from global (blocked layout [kblk][256][32] makes each warp's fragment a
// coalesced 1KB wave-load; L2-resident). LDS 11.5KB -> high occupancy; the
// MFMA accumulation order is identical to round 4/6 (bit-identical results).
// ---------------------------------------------------------------------------
template<int MODE, bool RELU, bool SPLITC, bool WSCALE, int NX>
__global__ __launch_bounds__(256) void gemm_f16x3(
    const float* __restrict__ A,
    const float* __restrict__ S0, const float* __restrict__ S1, const float* __restrict__ S2,
    const int* __restrict__ ridx, const int* __restrict__ cidx,
    const f16* __restrict__ BgH, const f16* __restrict__ BgL,
    const float* __restrict__ bias,
    const float* __restrict__ sc0, const float* __restrict__ sc1, const float* __restrict__ sc2,
    float* __restrict__ Clo, float* __restrict__ Chi,
    float* __restrict__ scOut, int K)
{
    __shared__ __align__(16) f16 Ah[64 * 40], Al[64 * 40];
    __shared__ float scL[64];
    __shared__ float rmL[64][4];

    const int tid = threadIdx.x;
    const int m0 = blockIdx.x * 64;
    const int arow = tid >> 2, aoct = tid & 3;
    const int w = tid >> 6, lane = tid & 63, lr = lane & 15, lh = lane >> 4;

    if (tid < 64) {
        float sc;
        if constexpr (MODE == 0) sc = sc0[m0 + tid];
        else if constexpr (MODE == 1) {
            int r = ridx[m0 + tid], cc = cidx[m0 + tid];
            sc = fminf(sc0[r], sc1[cc]) * 0.5f;
        } else if constexpr (MODE == 2) {
            sc = fminf(fminf(sc0[m0 + tid], sc1[m0 + tid]), sc2[m0 + tid]);
        } else {
            sc = sc0[cidx[m0 + tid]];
        }
        scL[tid] = sc;
    }
    int rI = 0, cI = 0;
    if constexpr (MODE == 1) { rI = ridx[m0 + arow]; cI = cidx[m0 + arow]; }
    __syncthreads();
    const float myS = scL[arow];

    float va[8];
    gemmLoadA<MODE>(A, S0, S1, S2, rI, cI, m0 + arow, K, aoct * 8, va);

    f32x4 acc[4][4] = {};
    for (int k0 = 0; k0 < K; k0 += 32) {
        // convert + store A tile
        {
            f16x8 hi, lo;
#pragma unroll
            for (int e = 0; e < 8; e++) {
                float a = va[e] * myS;
                f16 h = (f16)a;
                hi[e] = h;
                if constexpr (NX == 3) lo[e] = (f16)(a - (float)h);
            }
            *(f16x8*)&Ah[arow * 40 + aoct * 8] = hi;
            if constexpr (NX == 3) *(f16x8*)&Al[arow * 40 + aoct * 8] = lo;
        }
        __syncthreads();
        // prefetch next A (overlaps B loads + MFMA)
        if (k0 + 32 < K)
            gemmLoadA<MODE>(A, S0, S1, S2, rI, cI, m0 + arow, K, k0 + 32 + aoct * 8, va);
        // B fragments: direct coalesced global loads (L2-resident weights)
        f16x8 fbh[4], fbl[4];
        {
            size_t kbase = (size_t)(k0 >> 5) * 256;
#pragma unroll
            for (int j = 0; j < 4; j++) {
                size_t o = (kbase + (w * 64 + j * 16 + lr)) * 32 + lh * 8;
                fbh[j] = *(const f16x8*)(BgH + o);
                if constexpr (NX == 3) fbl[j] = *(const f16x8*)(BgL + o);
            }
        }
        // A fragments from LDS
        f16x8 fah[4], fal[4];
#pragma unroll
        for (int i = 0; i < 4; i++) {
            fah[i] = *(const f16x8*)&Ah[(i * 16 + lr) * 40 + lh * 8];
            if constexpr (NX == 3) fal[i] = *(const f16x8*)&Al[(i * 16 + lr) * 40 + lh * 8];
        }
#pragma unroll
        for (int j = 0; j < 4; j++) {
            if constexpr (NX == 3) {
#pragma unroll
                for (int i = 0; i < 4; i++) {
                    acc[i][j] = MFMA16(fah[i], fbh[j], acc[i][j]);
                    acc[i][j] = MFMA16(fah[i], fbl[j], acc[i][j]);
                    acc[i][j] = MFMA16(fal[i], fbh[j], acc[i][j]);
                }
            } else {
#pragma unroll
                for (int i = 0; i < 4; i++)
                    acc[i][j] = MFMA16(fah[i], fbh[j], acc[i][j]);
            }
        }
        __syncthreads();
    }

    float rm[4][4];
#pragma unroll
    for (int i = 0; i < 4; i++)
#pragma unroll
        for (int e = 0; e < 4; e++) rm[i][e] = 0.f;
#pragma unroll
    for (int i = 0; i < 4; i++) {
#pragma unroll
        for (int e = 0; e < 4; e++) {
            int ml = i * 16 + lh * 4 + e;
            int m = m0 + ml;
            float inv = DSB / scL[ml];
            float* Cb;
            if constexpr (SPLITC)
                Cb = (m < NNODES) ? (Clo + (size_t)m * HH) : (Chi + (size_t)(m - NNODES) * HH);
            else
                Cb = Clo + (size_t)m * HH;
#pragma unroll
            for (int j = 0; j < 4; j++) {
                int n = w * 64 + j * 16 + lr;
                float v = acc[i][j][e] * inv + bias[n];
                if constexpr (RELU) v = fmaxf(v, 0.f);
                Cb[n] = v;
                if constexpr (WSCALE) rm[i][e] = fmaxf(rm[i][e], fabsf(v));
            }
        }
    }
    if constexpr (WSCALE) {
#pragma unroll
        for (int i = 0; i < 4; i++)
#pragma unroll
            for (int e = 0; e < 4; e++) {
                float v = rm[i][e];
                v = fmaxf(v, __shfl_xor(v, 1));
                v = fmaxf(v, __shfl_xor(v, 2));
                v = fmaxf(v, __shfl_xor(v, 4));
                v = fmaxf(v, __shfl_xor(v, 8));
                if (lr == 0) rmL[i * 16 + lh * 4 + e][w] = v;
            }
        __syncthreads();
        if (tid < 64)
            scOut[m0 + tid] = sc_from_max(fmaxf(fmaxf(rmL[tid][0], rmL[tid][1]),
                                                fmaxf(rmL[tid][2], rmL[tid][3])));
    }
}

// ---------------------------------------------------------------------------
// GRU step v5: x3 precision (round-6 numerics, bit-identical accumulation
// order), BK=64 windows, B fragments loaded DIRECTLY from global (no B LDS).
// Grid 512 = 8 col-tiles(128) x 2 dirs x 32 g-tiles; id&7=c pins B per XCD L2.
// ---------------------------------------------------------------------------
__global__ __launch_bounds__(256) void gru_step_f16(
    const float* __restrict__ msgP, const f16* __restrict__ BgH, const f16* __restrict__ BgL,
    const float* __restrict__ bias4, const float* __restrict__ hidC, float* __restrict__ hidN,
    const float* __restrict__ scG, const int* __restrict__ starts, const int* __restrict__ gcnt,
    float* __restrict__ outF, float* __restrict__ outB, int t)
{
    __shared__ __align__(16) char smemraw[16896];
    f16* Ah = (f16*)smemraw;            // [32][72] (BK=64 + pad)
    f16* Al = Ah + 32 * 72;
    float* Cs = (float*)smemraw;        // [32*132] union, used after barrier
    __shared__ float scL[32];

    const int tid = threadIdx.x;
    const int id = blockIdx.x;
    const int c = id & 7, d = (id >> 3) & 1, gt = id >> 4;
    const int g0 = gt * 32;
    const int l = d ? (LL - 1 - t) : t;
    const float* hidCd = hidC + (size_t)d * GG * HH;
    float* hidNd = hidN + (size_t)d * GG * HH;

    if (tid < 32) scL[tid] = scG[g0 + tid];
    __syncthreads();

    const int arow = tid >> 3, akoct = tid & 7;   // A: 32 rows x 8 octets (64 k)
    const float myS = scL[arow];
    const int w = tid >> 6, lane = tid & 63, lr = lane & 15, lh = lane >> 4;

    float va[8];
    // prologue (window 0: k in [0,64) -> msgP)
    {
        const float* p = msgP + ((size_t)l * GG + g0 + arow) * HH + akoct * 8;
        float4 v0 = *(const float4*)p, v1 = *(const float4*)(p + 4);
        va[0]=v0.x; va[1]=v0.y; va[2]=v0.z; va[3]=v0.w;
        va[4]=v1.x; va[5]=v1.y; va[6]=v1.z; va[7]=v1.w;
    }

    f32x4 acc[2][2] = {};
    for (int win = 0; win < 8; win++) {
        {
            f16x8 hi, lo;
#pragma unroll
            for (int e = 0; e < 8; e++) {
                float a = va[e] * myS;
                f16 h = (f16)a;
                hi[e] = h;
                lo[e] = (f16)(a - (float)h);
            }
            *(f16x8*)&Ah[arow * 72 + akoct * 8] = hi;
            *(f16x8*)&Al[arow * 72 + akoct * 8] = lo;
        }
        __syncthreads();
        // prefetch next window's A
        if (win < 7) {
            int k = (win + 1) * 64 + akoct * 8;
            const float* p = (k < 256)
                ? msgP + ((size_t)l * GG + g0 + arow) * HH + k
                : hidCd + (size_t)(g0 + arow) * HH + (k - 256);
            float4 v0 = *(const float4*)p, v1 = *(const float4*)(p + 4);
            va[0]=v0.x; va[1]=v0.y; va[2]=v0.z; va[3]=v0.w;
            va[4]=v1.x; va[5]=v1.y; va[6]=v1.z; va[7]=v1.w;
        }
        // B fragments for both 32-k subblocks: direct global (XCD-L2-pinned)
        f16x8 fbh[2][2], fbl[2][2];
#pragma unroll
        for (int ks = 0; ks < 2; ks++) {
            size_t kbase = (size_t)(d * 16 + win * 2 + ks) * 1024;
#pragma unroll
            for (int j = 0; j < 2; j++) {
                size_t o = (kbase + (c * 128 + w * 32 + j * 16 + lr)) * 32 + lh * 8;
                fbh[ks][j] = *(const f16x8*)(BgH + o);
                fbl[ks][j] = *(const f16x8*)(BgL + o);
            }
        }
        // MFMA: 32-k subblocks in order (bit-identical to round-6 kb sequence)
#pragma unroll
        for (int ks = 0; ks < 2; ks++) {
            f16x8 fah[2], fal[2];
#pragma unroll
            for (int i = 0; i < 2; i++) {
                fah[i] = *(const f16x8*)&Ah[(i * 16 + lr) * 72 + ks * 32 + lh * 8];
                fal[i] = *(const f16x8*)&Al[(i * 16 + lr) * 72 + ks * 32 + lh * 8];
            }
#pragma unroll
            for (int j = 0; j < 2; j++) {
#pragma unroll
                for (int i = 0; i < 2; i++) {
                    acc[i][j] = MFMA16(fah[i], fbh[ks][j], acc[i][j]);
                    acc[i][j] = MFMA16(fah[i], fbl[ks][j], acc[i][j]);
                    acc[i][j] = MFMA16(fal[i], fbh[ks][j], acc[i][j]);
                }
            }
        }
        __syncthreads();
    }

    // stage descaled gate pre-activations: Cs[g_local][col_local], stride 132
#pragma unroll
    for (int i = 0; i < 2; i++) {
#pragma unroll
        for (int e = 0; e < 4; e++) {
            int ml = i * 16 + lh * 4 + e;
            float inv = DSB / scL[ml];
#pragma unroll
            for (int j = 0; j < 2; j++)
                Cs[ml * 132 + w * 32 + j * 16 + lr] = acc[i][j][e] * inv;
        }
    }
    __syncthreads();

    // gate epilogue: jj-major mapping for coalesced hid/out stores
    const float* b4 = bias4 + d * 1024;
    const int jl = tid & 31;
    const int J  = c * 32 + jl;
    const int gbase = (tid >> 5) * 4;
    const float bb0 = b4[4 * J + 0], bb1 = b4[4 * J + 1];
    const float bb2 = b4[4 * J + 2], bb3 = b4[4 * J + 3];
    float* o = d ? outB : outF;
#pragma unroll
    for (int i = 0; i < 4; i++) {
        int gl = gbase + i;
        int g = g0 + gl;
        f32x4 gv = *(const f32x4*)&Cs[gl * 132 + jl * 4];
        float r = 1.f / (1.f + expf(-(gv[0] + bb0)));
        float z = 1.f / (1.f + expf(-(gv[1] + bb1)));
        float nn = tanhf(gv[2] + bb2 + r * (gv[3] + bb3));
        float hp = hidCd[(size_t)g * HH + J];
        float hnew = (1.f - z) * nn + z * hp;
        hidNd[(size_t)g * HH + J] = hnew;
        if (l < gcnt[g]) o[(size_t)(starts[g] + l) * HH + J] = hnew;
    }
}

__global__ void fill_sentinel(float* __restrict__ out, float v)
{
    size_t idx = (size_t)blockIdx.x * 256 + threadIdx.x;
    out[idx] = v;
}

// ---------------------------------------------------------------------------
// Workspace layout identical to round 3-6 (verified):
//  W0 h_atom -> outF | W1 bondA.lo -> aggr -> outB | W1h bondA.hi -> x_proj -> msgP
//  W2 bondB.lo -> h/msg | d_out: bondB.hi -> {hid0,hid1,bias4,BgH,BgL} -> final out
// ---------------------------------------------------------------------------
extern "C" void kernel_launch(void* const* d_in, const int* in_sizes, int n_in,
                              void* d_out, int out_size, void* d_ws, size_t ws_size,
                              hipStream_t stream)
{
    (void)in_sizes; (void)n_in; (void)out_size;
    const float* x         = (const float*)d_in[0];
    const float* edge_attr = (const float*)d_in[1];
    const int*   eidx      = (const int*)d_in[2];
    const int*   batch     = (const int*)d_in[3];
    const float* w_atom    = (const float*)d_in[4];
    const float* b_atom    = (const float*)d_in[5];
    const float* w_bond    = (const float*)d_in[6];
    const float* b_bond    = (const float*)d_in[7];
    const float* conv_w    = (const float*)d_in[8];
    const float* conv_b    = (const float*)d_in[9];
    const float* w_lin     = (const float*)d_in[10];
    const float* b_lin     = (const float*)d_in[11];
    const float* gru_bias  = (const float*)d_in[12];
    const float* w_ih      = (const float*)d_in[13];
    const float* w_hh      = (const float*)d_in[14];
    const float* b_ih      = (const float*)d_in[15];
    const float* b_hh      = (const float*)d_in[16];
    const float* w_out     = (const float*)d_in[17];
    const float* b_out     = (const float*)d_in[18];

    const int* row = eidx;
    const int* col = eidx + NEDGES;

    const size_t NH = (size_t)NNODES * HH;

    float* W   = (float*)d_ws;
    float* W0  = W;
    float* W1  = W + NH;
    float* W1h = W + 2 * NH;
    float* W2  = W + 3 * NH;
    float* DO  = (float*)d_out;

    size_t off = 4 * NH;
    int* counts  = (int*)(W + off);      off += NNODES;
    int* cursor  = (int*)(W + off);      off += NNODES;
    int* gcnt    = (int*)(W + off);      off += GG;
    int* starts  = (int*)(W + off);      off += GG;
    int* offsets = (int*)(W + off);      off += NNODES + 1;
    int* elist   = (int*)(W + off);      off += NEDGES;
    float* scX    = W + off;             off += NNODES;
    float* scEA   = W + off;             off += NEDGES;
    float* scHbA  = W + off;             off += NEDGES;
    float* scHbB  = W + off;             off += NEDGES;
    float* scAtom = W + off;             off += NNODES;
    float* scAggr = W + off;             off += NNODES;
    float* scXp   = W + off;             off += NNODES;
    float* scGru  = W + off;             off += GG;
    off = (off + 3) & ~(size_t)3;
    f16* fp = (f16*)(W + off);
    f16* watomH = fp;                     fp += 4 * 256 * 32;
    f16* watomL = fp;                     fp += 4 * 256 * 32;
    f16* wbondH = fp;                     fp += 2 * 256 * 32;
    f16* wbondL = fp;                     fp += 2 * 256 * 32;
    f16* convH[3]; f16* convL[3];
    for (int i = 0; i < 3; i++) { convH[i] = fp; fp += 8 * 256 * 32; convL[i] = fp; fp += 8 * 256 * 32; }
    f16* wlinH = fp;                      fp += 24 * 256 * 32;
    f16* wlinL = fp;                      fp += 24 * 256 * 32;
    f16* woutH = fp;                      fp += 16 * 256 * 32;
    f16* woutL = fp;                      fp += 16 * 256 * 32;

    const size_t NEED = (char*)fp - (char*)d_ws;
    if (ws_size < NEED) {
        fill_sentinel<<<(int)(NH / 256), 256, 0, stream>>>((float*)d_out, (float)ws_size);
        return;
    }

    // d_out overlay (dead between final booster and final GEMM)
    float* hid0  = DO;
    float* hid1  = DO + 2 * (size_t)GG * HH;
    float* bias4 = DO + 4 * (size_t)GG * HH;
    f16* BgH = (f16*)(bias4 + 2048);
    f16* BgL = BgH + (size_t)2 * 16 * 1024 * 32;

    hipMemsetAsync(counts, 0, (size_t)(2 * NNODES + 2 * GG) * sizeof(int), stream);
    prep_graphs<<<(NNODES + 255) / 256, 256, 0, stream>>>(batch, starts, gcnt);
    csr_count<<<(NEDGES + 255) / 256, 256, 0, stream>>>(row, counts);
    scan_offsets<<<1, 1024, 0, stream>>>(counts, offsets);
    csr_fill<<<(NEDGES + 255) / 256, 256, 0, stream>>>(row, offsets, cursor, elist);

    rowscale<<<NNODES, 64, 0, stream>>>(x, 128, scX);
    rowscale<<<NEDGES, 64, 0, stream>>>(edge_attr, 64, scEA);

    prep_wT<<<128, 256, 0, stream>>>(w_atom, watomH, watomL);
    prep_wT<<<64, 256, 0, stream>>>(w_bond, wbondH, wbondL);
    for (int i = 0; i < 3; i++)
        prep_wT<<<256, 256, 0, stream>>>(conv_w + (size_t)i * HH * HH, convH[i], convL[i]);
    prep_wT<<<768, 256, 0, stream>>>(w_lin, wlinH, wlinL);
    prep_wT<<<512, 256, 0, stream>>>(w_out, woutH, woutL);

    // x_proj = relu(x @ w_atom + b_atom) -> W0, scAtom
    gemm_f16x3<0, true, false, true, 3><<<NNODES / 64, 256, 0, stream>>>(
        x, nullptr, nullptr, nullptr, nullptr, nullptr, watomH, watomL, b_atom,
        scX, nullptr, nullptr, W0, nullptr, scAtom, 128);
    // bondA = relu(edge_attr @ w_bond + b_bond) -> (W1, W1h), scHbA
    gemm_f16x3<0, true, true, true, 3><<<NEDGES / 64, 256, 0, stream>>>(
        edge_attr, nullptr, nullptr, nullptr, nullptr, nullptr, wbondH, wbondL, b_bond,
        scEA, nullptr, nullptr, W1, W1h, scHbA, 64);

    float* cur_lo = W1; float* cur_hi = W1h; float* cur_sc = scHbA;
    float* nxt_lo = W2; float* nxt_hi = DO;  float* nxt_sc = scHbB;
    for (int i = 0; i < 3; i++) {
        booster<<<NNODES, 256, 0, stream>>>(cur_lo, cur_hi, W0, W0, offsets, elist, scAtom);
        gemm_f16x3<1, true, true, true, 3><<<NEDGES / 64, 256, 0, stream>>>(
            nullptr, W0, cur_lo, nullptr, row, col, convH[i], convL[i],
            conv_b + (size_t)i * HH, scAtom, cur_sc, nullptr, nxt_lo, nxt_hi, nxt_sc, 256);
        float* t0 = cur_lo; cur_lo = nxt_lo; nxt_lo = t0;
        float* t1 = cur_hi; cur_hi = nxt_hi; nxt_hi = t1;
        float* t2 = cur_sc; cur_sc = nxt_sc; nxt_sc = t2;
    }
    // aggr = h_atom + booster(bondB) -> W1 (bondA dead)
    booster<<<NNODES, 256, 0, stream>>>(cur_lo, cur_hi, W0, W1, offsets, elist, scAggr);
    // recompute x_proj -> W1h
    gemm_f16x3<0, true, false, true, 3><<<NNODES / 64, 256, 0, stream>>>(
        x, nullptr, nullptr, nullptr, nullptr, nullptr, watomH, watomL, b_atom,
        scX, nullptr, nullptr, W1h, nullptr, scXp, 128);
    // h = concat(aggr, h_atom, x_proj) @ w_lin + b_lin -> W2
    gemm_f16x3<2, false, false, false, 3><<<NNODES / 64, 256, 0, stream>>>(
        nullptr, W1, W0, W1h, nullptr, nullptr, wlinH, wlinL, b_lin,
        scAggr, scAtom, scXp, W2, nullptr, nullptr, 768);

    // GRU prep (DO bond rows dead now)
    h0_init<<<GG, 256, 0, stream>>>(W2, starts, gcnt, hid0, scGru);
    build_msgP<<<dim3(LL, GG), 256, 0, stream>>>(W2, gru_bias, starts, gcnt, W1h);
    prep_gruW<<<(2 * 512 * 1024) / 256, 256, 0, stream>>>(w_ih, w_hh, b_ih, b_hh, BgH, BgL, bias4);

    for (int t = 0; t < LL; t++) {
        float* hc = (t & 1) ? hid1 : hid0;
        float* hx = (t & 1) ? hid0 : hid1;
        gru_step_f16<<<512, 256, 0, stream>>>(W1h, BgH, BgL, bias4, hc, hx,
                                              scGru, starts, gcnt, W0, W1, t);
    }

    // out = relu(concat(outF, outB) @ w_out + b_out), pure f16 (NX=1)
    gemm_f16x3<3, true, false, false, 1><<<NNODES / 64, 256, 0, stream>>>(
        nullptr, W0, W1, nullptr, nullptr, batch, woutH, nullptr, b_out,
        scGru, nullptr, nullptr, (float*)d_out, nullptr, nullptr, 512);
}

// Round 9
// 1474.228 us; speedup vs baseline: 1.1524x; 1.1524x over previous
//
#include <hip/hip_runtime.h>
#include <math.h>

#define HH 256
#define GG 1024
#define LL 48
#define NNODES 49152   // G*L
#define NEDGES 98304   // 2*N
#define SB 256.0f      // weight-side scale 2^8
#define DSB 0.00390625f // 2^-8

typedef _Float16 f16;
typedef __attribute__((ext_vector_type(8))) _Float16 f16x8;
typedef __attribute__((ext_vector_type(4))) float f32x4;

#define MFMA16(a, b, c) __builtin_amdgcn_mfma_f32_16x16x32_f16(a, b, c, 0, 0, 0)

__device__ inline float sc_from_max(float m) {
    if (!(m > 0.f)) return 1.0f;
    return ldexpf(1.0f, 13 - ilogbf(m));   // m*sc in [2^13, 2^14)
}

// ---------------------------------------------------------------------------
// CSR build (verified round 2-6)
// ---------------------------------------------------------------------------
__global__ void csr_count(const int* __restrict__ row, int* __restrict__ counts)
{
    int e = blockIdx.x * 256 + threadIdx.x;
    if (e < NEDGES) atomicAdd(&counts[row[e]], 1);
}

__global__ __launch_bounds__(1024) void scan_offsets(const int* __restrict__ counts,
                                                     int* __restrict__ offsets)
{
    __shared__ int tsum[1024];
    const int tid = threadIdx.x;
    const int base = tid * 48;
    int s = 0;
    for (int i = 0; i < 48; i++) s += counts[base + i];
    tsum[tid] = s;
    __syncthreads();
    for (int off = 1; off < 1024; off <<= 1) {
        int v = (tid >= off) ? tsum[tid - off] : 0;
        __syncthreads();
        tsum[tid] += v;
        __syncthreads();
    }
    int run = (tid == 0) ? 0 : tsum[tid - 1];
    for (int i = 0; i < 48; i++) { offsets[base + i] = run; run += counts[base + i]; }
    if (tid == 1023) offsets[NNODES] = run;
}

__global__ void csr_fill(const int* __restrict__ row, const int* __restrict__ offsets,
                         int* __restrict__ cursor, int* __restrict__ elist)
{
    int e = blockIdx.x * 256 + threadIdx.x;
    if (e < NEDGES) {
        int r = row[e];
        int p = atomicAdd(&cursor[r], 1);
        elist[offsets[r] + p] = e;
    }
}

__global__ void prep_graphs(const int* __restrict__ batch, int* __restrict__ starts,
                            int* __restrict__ gcnt)
{
    int i = blockIdx.x * 256 + threadIdx.x;
    if (i < NNODES) {
        int b = batch[i];
        atomicAdd(&gcnt[b], 1);
        if (i == 0 || batch[i - 1] != b) starts[b] = i;
    }
}

__global__ void rowscale(const float* __restrict__ A, int K, float* __restrict__ sc)
{
    int m = blockIdx.x, ln = threadIdx.x;
    float v = 0.f;
    for (int k = ln; k < K; k += 64) v = fmaxf(v, fabsf(A[(size_t)m * K + k]));
    for (int s = 32; s; s >>= 1) v = fmaxf(v, __shfl_xor(v, s));
    if (ln == 0) sc[m] = sc_from_max(v);
}

// weight prep: W[K][256] f32 -> blocked transposed f16 hi/lo [kblk][256][32], x2^8
__global__ void prep_wT(const float* __restrict__ Wsrc, f16* __restrict__ oH,
                        f16* __restrict__ oL)
{
    int idx = blockIdx.x * 256 + threadIdx.x;
    int k = idx >> 8, n = idx & 255;
    float v = Wsrc[(size_t)k * 256 + n] * SB;
    f16 h = (f16)v;
    size_t o = ((size_t)(k >> 5) * 256 + n) * 32 + (k & 31);
    oH[o] = h;
    oL[o] = (f16)(v - (float)h);
}

// GRU weight prep: cols interleaved 4*jj+s; blocked [d][kblk][1024][32] hi/lo
__global__ void prep_gruW(const float* __restrict__ w_ih, const float* __restrict__ w_hh,
                          const float* __restrict__ b_ih, const float* __restrict__ b_hh,
                          f16* __restrict__ BgH, f16* __restrict__ BgL,
                          float* __restrict__ bias4)
{
    int idx = blockIdx.x * 256 + threadIdx.x;   // 2*512*1024
    int d = idx >> 19;
    int rem = idx & 524287;
    int k = rem >> 10;
    int col = rem & 1023;
    int jj = col >> 2, s = col & 3;
    const float* Wi = w_ih + (size_t)d * 768 * 256;
    const float* Wh = w_hh + (size_t)d * 768 * 256;
    float v;
    if (s == 0)      v = (k < 256) ? Wi[(size_t)jj * 256 + k]         : Wh[(size_t)jj * 256 + (k - 256)];
    else if (s == 1) v = (k < 256) ? Wi[(size_t)(256 + jj) * 256 + k] : Wh[(size_t)(256 + jj) * 256 + (k - 256)];
    else if (s == 2) v = (k < 256) ? Wi[(size_t)(512 + jj) * 256 + k] : 0.f;
    else             v = (k < 256) ? 0.f : Wh[(size_t)(512 + jj) * 256 + (k - 256)];
    v *= SB;
    f16 h = (f16)v;
    size_t o = ((size_t)(d * 16 + (k >> 5)) * 1024 + col) * 32 + (k & 31);
    BgH[o] = h;
    BgL[o] = (f16)(v - (float)h);
    if (k == 0) {
        const float* bi = b_ih + d * 768;
        const float* bh = b_hh + d * 768;
        float bv;
        if (s == 0)      bv = bi[jj] + bh[jj];
        else if (s == 1) bv = bi[256 + jj] + bh[256 + jj];
        else if (s == 2) bv = bi[512 + jj];
        else             bv = bh[512 + jj];
        bias4[d * 1024 + col] = bv;
    }
}

// booster + per-node scale (verified round 3-6)
__global__ void booster(const float* __restrict__ hb_lo, const float* __restrict__ hb_hi,
                        const float* __restrict__ atom_in, float* __restrict__ out,
                        const int* __restrict__ offsets, const int* __restrict__ elist,
                        float* __restrict__ scOut)
{
    int n = blockIdx.x, c = threadIdx.x;
    int b0 = offsets[n], b1 = offsets[n + 1];
    float s = 0.f, m = 0.f;
    for (int p = b0; p < b1; p++) {
        int e = elist[p];
        const float* hb = (e < NNODES) ? (hb_lo + (size_t)e * HH)
                                       : (hb_hi + (size_t)(e - NNODES) * HH);
        float v = hb[c];
        s += v;
        m = fmaxf(m, v);
    }
    float o = atom_in[(size_t)n * HH + c] + s * m;
    out[(size_t)n * HH + c] = o;
    float v = fabsf(o);
    for (int t = 32; t; t >>= 1) v = fmaxf(v, __shfl_xor(v, t));
    __shared__ float wm[4];
    if ((c & 63) == 0) wm[c >> 6] = v;
    __syncthreads();
    if (c == 0)
        scOut[n] = sc_from_max(fmaxf(fmaxf(wm[0], wm[1]), fmaxf(wm[2], wm[3])));
}

__global__ void h0_init(const float* __restrict__ h, const int* __restrict__ starts,
                        const int* __restrict__ gcnt, float* __restrict__ hid0,
                        float* __restrict__ scG)
{
    int g = blockIdx.x, c = threadIdx.x;
    int st = starts[g], cn = gcnt[g];
    float m = -INFINITY, am = 0.f;
    for (int i = 0; i < cn; i++) {
        float v = h[(size_t)(st + i) * HH + c];
        m = fmaxf(m, v);
        am = fmaxf(am, fabsf(v));
    }
    if (cn == 0) m = 0.f;
    hid0[(size_t)g * HH + c] = m;
    hid0[(size_t)GG * HH + (size_t)g * HH + c] = m;
    for (int t = 32; t; t >>= 1) am = fmaxf(am, __shfl_xor(am, t));
    __shared__ float wm[4];
    if ((c & 63) == 0) wm[c >> 6] = am;
    __syncthreads();
    if (c == 0) {
        float M = fmaxf(fmaxf(fmaxf(wm[0], wm[1]), fmaxf(wm[2], wm[3])) + 0.07f, 1.0f);
        scG[g] = sc_from_max(M);
    }
}

// msgP[l][g][k] = relu(h[starts[g]+l][k] + gru_bias[k]) (0 for invalid l)
__global__ void build_msgP(const float* __restrict__ h, const float* __restrict__ gbias,
                           const int* __restrict__ starts, const int* __restrict__ gcnt,
                           float* __restrict__ msgP)
{
    int l = blockIdx.x, g = blockIdx.y, k = threadIdx.x;
    float v = 0.f;
    if (l < gcnt[g]) {
        int node = starts[g] + l;
        v = fmaxf(h[(size_t)node * HH + k] + gbias[k], 0.f);
    }
    msgP[((size_t)l * GG + g) * HH + k] = v;
}

// ---------------------------------------------------------------------------
// A-tile element loaders (8 consecutive k of one row)
// ---------------------------------------------------------------------------
template<int MODE>
__device__ __forceinline__ void gemmLoadA(const float* __restrict__ A,
    const float* __restrict__ S0, const float* __restrict__ S1,
    const float* __restrict__ S2, int rI, int cI, int row, int K, int k,
    float va[8])
{
    if constexpr (MODE == 0) {
        const float* p = A + (size_t)row * K + k;
        float4 v0 = *(const float4*)p, v1 = *(const float4*)(p + 4);
        va[0]=v0.x; va[1]=v0.y; va[2]=v0.z; va[3]=v0.w;
        va[4]=v1.x; va[5]=v1.y; va[6]=v1.z; va[7]=v1.w;
    } else if constexpr (MODE == 1) {
        const float* pa = S0 + (size_t)rI * HH + k;
        const float* pb = S1 + (size_t)cI * HH + k;
        float4 a0 = *(const float4*)pa, a1 = *(const float4*)(pa + 4);
        float4 b0 = *(const float4*)pb, b1 = *(const float4*)(pb + 4);
        va[0]=a0.x-b0.x; va[1]=a0.y-b0.y; va[2]=a0.z-b0.z; va[3]=a0.w-b0.w;
        va[4]=a1.x-b1.x; va[5]=a1.y-b1.y; va[6]=a1.z-b1.z; va[7]=a1.w-b1.w;
    } else if constexpr (MODE == 2) {
        const float* S = (k < 256) ? S0 : ((k < 512) ? S1 : S2);
        const float* p = S + (size_t)row * HH + (k & 255);
        float4 v0 = *(const float4*)p, v1 = *(const float4*)(p + 4);
        va[0]=v0.x; va[1]=v0.y; va[2]=v0.z; va[3]=v0.w;
        va[4]=v1.x; va[5]=v1.y; va[6]=v1.z; va[7]=v1.w;
    } else {
        const float* S = (k < 256) ? S0 : S1;
        const float* p = S + (size_t)row * HH + (k & 255);
        float4 v0 = *(const float4*)p, v1 = *(const float4*)(p + 4);
        va[0]=v0.x; va[1]=v0.y; va[2]=v0.z; va[3]=v0.w;
        va[4]=v1.x; va[5]=v1.y; va[6]=v1.z; va[7]=v1.w;
    }
}

// ---------------------------------------------------------------------------
// f16 split MFMA GEMM with register prefetch — EXACT round-6 version
// (verified, w_lin 102 us).
// ---------------------------------------------------------------------------
template<int MODE, bool RELU, bool SPLITC, bool WSCALE, int NX>
__global__ __launch_bounds__(256) void gemm_f16x3(
    const float* __restrict__ A,
    const float* __restrict__ S0, const float* __restrict__ S1, const float* __restrict__ S2,
    const int* __restrict__ ridx, const int* __restrict__ cidx,
    const f16* __restrict__ BgH, const f16* __restrict__ BgL,
    const float* __restrict__ bias,
    const float* __restrict__ sc0, const float* __restrict__ sc1, const float* __restrict__ sc2,
    float* __restrict__ Clo, float* __restrict__ Chi,
    float* __restrict__ scOut, int K)
{
    __shared__ __align__(16) f16 Ah[64 * 40], Al[64 * 40];
    __shared__ __align__(16) f16 Bh[256 * 40], Bl[256 * 40];
    __shared__ float scL[64];
    __shared__ float rmL[64][4];

    const int tid = threadIdx.x;
    const int m0 = blockIdx.x * 64;
    const int arow = tid >> 2, aoct = tid & 3;
    const int w = tid >> 6, lane = tid & 63, lr = lane & 15, lh = lane >> 4;

    if (tid < 64) {
        float sc;
        if constexpr (MODE == 0) sc = sc0[m0 + tid];
        else if constexpr (MODE == 1) {
            int r = ridx[m0 + tid], cc = cidx[m0 + tid];
            sc = fminf(sc0[r], sc1[cc]) * 0.5f;
        } else if constexpr (MODE == 2) {
            sc = fminf(fminf(sc0[m0 + tid], sc1[m0 + tid]), sc2[m0 + tid]);
        } else {
            sc = sc0[cidx[m0 + tid]];
        }
        scL[tid] = sc;
    }
    int rI = 0, cI = 0;
    if constexpr (MODE == 1) { rI = ridx[m0 + arow]; cI = cidx[m0 + arow]; }
    __syncthreads();
    const float myS = scL[arow];

    float va[8];
    f16x8 rbh[4], rbl[4];
    gemmLoadA<MODE>(A, S0, S1, S2, rI, cI, m0 + arow, K, aoct * 8, va);
    {
        size_t base = (size_t)tid * 32;
        const f16x8* ph = (const f16x8*)(BgH + base);
#pragma unroll
        for (int q = 0; q < 4; q++) rbh[q] = ph[q];
        if constexpr (NX == 3) {
            const f16x8* pl = (const f16x8*)(BgL + base);
#pragma unroll
            for (int q = 0; q < 4; q++) rbl[q] = pl[q];
        }
    }

    f32x4 acc[4][4] = {};
    for (int k0 = 0; k0 < K; k0 += 32) {
        {
            f16x8 hi, lo;
#pragma unroll
            for (int e = 0; e < 8; e++) {
                float a = va[e] * myS;
                f16 h = (f16)a;
                hi[e] = h;
                if constexpr (NX == 3) lo[e] = (f16)(a - (float)h);
            }
            *(f16x8*)&Ah[arow * 40 + aoct * 8] = hi;
            if constexpr (NX == 3) *(f16x8*)&Al[arow * 40 + aoct * 8] = lo;
        }
#pragma unroll
        for (int q = 0; q < 4; q++) {
            *(f16x8*)&Bh[tid * 40 + q * 8] = rbh[q];
            if constexpr (NX == 3) *(f16x8*)&Bl[tid * 40 + q * 8] = rbl[q];
        }
        __syncthreads();
        if (k0 + 32 < K) {
            gemmLoadA<MODE>(A, S0, S1, S2, rI, cI, m0 + arow, K, k0 + 32 + aoct * 8, va);
            size_t base = ((size_t)((k0 + 32) >> 5) * 256 + tid) * 32;
            const f16x8* ph = (const f16x8*)(BgH + base);
#pragma unroll
            for (int q = 0; q < 4; q++) rbh[q] = ph[q];
            if constexpr (NX == 3) {
                const f16x8* pl = (const f16x8*)(BgL + base);
#pragma unroll
                for (int q = 0; q < 4; q++) rbl[q] = pl[q];
            }
        }
        f16x8 fah[4], fal[4];
#pragma unroll
        for (int i = 0; i < 4; i++) {
            fah[i] = *(const f16x8*)&Ah[(i * 16 + lr) * 40 + lh * 8];
            if constexpr (NX == 3) fal[i] = *(const f16x8*)&Al[(i * 16 + lr) * 40 + lh * 8];
        }
#pragma unroll
        for (int j = 0; j < 4; j++) {
            int colx = w * 64 + j * 16 + lr;
            f16x8 fbh = *(const f16x8*)&Bh[colx * 40 + lh * 8];
            if constexpr (NX == 3) {
                f16x8 fbl = *(const f16x8*)&Bl[colx * 40 + lh * 8];
#pragma unroll
                for (int i = 0; i < 4; i++) {
                    acc[i][j] = MFMA16(fah[i], fbh, acc[i][j]);
                    acc[i][j] = MFMA16(fah[i], fbl, acc[i][j]);
                    acc[i][j] = MFMA16(fal[i], fbh, acc[i][j]);
                }
            } else {
#pragma unroll
                for (int i = 0; i < 4; i++)
                    acc[i][j] = MFMA16(fah[i], fbh, acc[i][j]);
            }
        }
        __syncthreads();
    }

    float rm[4][4];
#pragma unroll
    for (int i = 0; i < 4; i++)
#pragma unroll
        for (int e = 0; e < 4; e++) rm[i][e] = 0.f;
#pragma unroll
    for (int i = 0; i < 4; i++) {
#pragma unroll
        for (int e = 0; e < 4; e++) {
            int ml = i * 16 + lh * 4 + e;
            int m = m0 + ml;
            float inv = DSB / scL[ml];
            float* Cb;
            if constexpr (SPLITC)
                Cb = (m < NNODES) ? (Clo + (size_t)m * HH) : (Chi + (size_t)(m - NNODES) * HH);
            else
                Cb = Clo + (size_t)m * HH;
#pragma unroll
            for (int j = 0; j < 4; j++) {
                int n = w * 64 + j * 16 + lr;
                float v = acc[i][j][e] * inv + bias[n];
                if constexpr (RELU) v = fmaxf(v, 0.f);
                Cb[n] = v;
                if constexpr (WSCALE) rm[i][e] = fmaxf(rm[i][e], fabsf(v));
            }
        }
    }
    if constexpr (WSCALE) {
#pragma unroll
        for (int i = 0; i < 4; i++)
#pragma unroll
            for (int e = 0; e < 4; e++) {
                float v = rm[i][e];
                v = fmaxf(v, __shfl_xor(v, 1));
                v = fmaxf(v, __shfl_xor(v, 2));
                v = fmaxf(v, __shfl_xor(v, 4));
                v = fmaxf(v, __shfl_xor(v, 8));
                if (lr == 0) rmL[i * 16 + lh * 4 + e][w] = v;
            }
        __syncthreads();
        if (tid < 64)
            scOut[m0 + tid] = sc_from_max(fmaxf(fmaxf(rmL[tid][0], rmL[tid][1]),
                                                fmaxf(rmL[tid][2], rmL[tid][3])));
    }
}

// ---------------------------------------------------------------------------
// GRU step v6: x3 (round-6 numerics, bit-identical order); BK=64 windows,
// fully unrolled; B fragments direct-from-global with REGISTER double-buffer
// (next window prefetched during current MFMAs); A-LDS double-buffered ->
// ONE barrier per window (9 total vs 16). Grid 512 = 8c x 2d x 32gt.
// ---------------------------------------------------------------------------
__global__ __launch_bounds__(256) void gru_step_f16(
    const float* __restrict__ msgP, const f16* __restrict__ BgH, const f16* __restrict__ BgL,
    const float* __restrict__ bias4, const float* __restrict__ hidC, float* __restrict__ hidN,
    const float* __restrict__ scG, const int* __restrict__ starts, const int* __restrict__ gcnt,
    float* __restrict__ outF, float* __restrict__ outB, int t)
{
    __shared__ __align__(16) char smemraw[18432];   // 2 bufs x (Ah+Al) x 32x72 f16
    float* Cs = (float*)smemraw;                    // union (16896B), used after last read
    __shared__ float scL[32];

    const int tid = threadIdx.x;
    const int id = blockIdx.x;
    const int c = id & 7, d = (id >> 3) & 1, gt = id >> 4;
    const int g0 = gt * 32;
    const int l = d ? (LL - 1 - t) : t;
    const float* hidCd = hidC + (size_t)d * GG * HH;
    float* hidNd = hidN + (size_t)d * GG * HH;

    if (tid < 32) scL[tid] = scG[g0 + tid];
    __syncthreads();

    const int arow = tid >> 3, akoct = tid & 7;   // A: 32 rows x 8 octets (64 k)
    const float myS = scL[arow];
    const int w = tid >> 6, lane = tid & 63, lr = lane & 15, lh = lane >> 4;

    f16* Ah0 = (f16*)smemraw;
    f16* Al0 = Ah0 + 2304;
    f16* Ah1 = Al0 + 2304;
    f16* Al1 = Ah1 + 2304;

    // ---- prologue: window 0 A -> buf0; window 0 B -> regs
    {
        const float* p = msgP + ((size_t)l * GG + g0 + arow) * HH + akoct * 8;
        float4 v0 = *(const float4*)p, v1 = *(const float4*)(p + 4);
        float va0[8] = {v0.x, v0.y, v0.z, v0.w, v1.x, v1.y, v1.z, v1.w};
        f16x8 hi, lo;
#pragma unroll
        for (int e = 0; e < 8; e++) {
            float a = va0[e] * myS;
            f16 h = (f16)a;
            hi[e] = h;
            lo[e] = (f16)(a - (float)h);
        }
        *(f16x8*)&Ah0[arow * 72 + akoct * 8] = hi;
        *(f16x8*)&Al0[arow * 72 + akoct * 8] = lo;
    }
    f16x8 fbh[2][2], fbl[2][2];
#pragma unroll
    for (int ks = 0; ks < 2; ks++) {
        size_t kbase = (size_t)(d * 16 + ks) * 1024;
#pragma unroll
        for (int j = 0; j < 2; j++) {
            size_t o = (kbase + (c * 128 + w * 32 + j * 16 + lr)) * 32 + lh * 8;
            fbh[ks][j] = *(const f16x8*)(BgH + o);
            fbl[ks][j] = *(const f16x8*)(BgL + o);
        }
    }
    __syncthreads();

    f32x4 acc[2][2] = {};
#pragma unroll
    for (int win = 0; win < 8; win++) {
        f16* AhC = (win & 1) ? Ah1 : Ah0;
        f16* AlC = (win & 1) ? Al1 : Al0;
        f16* AhN = (win & 1) ? Ah0 : Ah1;
        f16* AlN = (win & 1) ? Al0 : Al1;

        // issue next-window A loads (global; consumed after MFMA)
        float va[8];
        if (win < 7) {
            int k = (win + 1) * 64 + akoct * 8;
            const float* p = (k < 256)
                ? msgP + ((size_t)l * GG + g0 + arow) * HH + k
                : hidCd + (size_t)(g0 + arow) * HH + (k - 256);
            float4 v0 = *(const float4*)p, v1 = *(const float4*)(p + 4);
            va[0]=v0.x; va[1]=v0.y; va[2]=v0.z; va[3]=v0.w;
            va[4]=v1.x; va[5]=v1.y; va[6]=v1.z; va[7]=v1.w;
        }
        // issue next-window B loads into fresh regs (latency hidden by MFMA)
        f16x8 nbh[2][2], nbl[2][2];
        if (win < 7) {
#pragma unroll
            for (int ks = 0; ks < 2; ks++) {
                size_t kbase = (size_t)(d * 16 + (win + 1) * 2 + ks) * 1024;
#pragma unroll
                for (int j = 0; j < 2; j++) {
                    size_t o = (kbase + (c * 128 + w * 32 + j * 16 + lr)) * 32 + lh * 8;
                    nbh[ks][j] = *(const f16x8*)(BgH + o);
                    nbl[ks][j] = *(const f16x8*)(BgL + o);
                }
            }
        }
        // MFMA on current window (A from LDS buf, B from regs) — round-6 order
#pragma unroll
        for (int ks = 0; ks < 2; ks++) {
            f16x8 fah[2], fal[2];
#pragma unroll
            for (int i = 0; i < 2; i++) {
                fah[i] = *(const f16x8*)&AhC[(i * 16 + lr) * 72 + ks * 32 + lh * 8];
                fal[i] = *(const f16x8*)&AlC[(i * 16 + lr) * 72 + ks * 32 + lh * 8];
            }
#pragma unroll
            for (int j = 0; j < 2; j++) {
#pragma unroll
                for (int i = 0; i < 2; i++) {
                    acc[i][j] = MFMA16(fah[i], fbh[ks][j], acc[i][j]);
                    acc[i][j] = MFMA16(fah[i], fbl[ks][j], acc[i][j]);
                    acc[i][j] = MFMA16(fal[i], fbh[ks][j], acc[i][j]);
                }
            }
        }
        // write next-window A into the other LDS buffer; roll B regs
        if (win < 7) {
            f16x8 hi, lo;
#pragma unroll
            for (int e = 0; e < 8; e++) {
                float a = va[e] * myS;
                f16 h = (f16)a;
                hi[e] = h;
                lo[e] = (f16)(a - (float)h);
            }
            *(f16x8*)&AhN[arow * 72 + akoct * 8] = hi;
            *(f16x8*)&AlN[arow * 72 + akoct * 8] = lo;
#pragma unroll
            for (int ks = 0; ks < 2; ks++)
#pragma unroll
                for (int j = 0; j < 2; j++) {
                    fbh[ks][j] = nbh[ks][j];
                    fbl[ks][j] = nbl[ks][j];
                }
        }
        __syncthreads();
    }

    // stage descaled gate pre-activations: Cs[g_local][col_local], stride 132
#pragma unroll
    for (int i = 0; i < 2; i++) {
#pragma unroll
        for (int e = 0; e < 4; e++) {
            int ml = i * 16 + lh * 4 + e;
            float inv = DSB / scL[ml];
#pragma unroll
            for (int j = 0; j < 2; j++)
                Cs[ml * 132 + w * 32 + j * 16 + lr] = acc[i][j][e] * inv;
        }
    }
    __syncthreads();

    // gate epilogue: jj-major mapping for coalesced hid/out stores
    const float* b4 = bias4 + d * 1024;
    const int jl = tid & 31;
    const int J  = c * 32 + jl;
    const int gbase = (tid >> 5) * 4;
    const float bb0 = b4[4 * J + 0], bb1 = b4[4 * J + 1];
    const float bb2 = b4[4 * J + 2], bb3 = b4[4 * J + 3];
    float* o = d ? outB : outF;
#pragma unroll
    for (int i = 0; i < 4; i++) {
        int gl = gbase + i;
        int g = g0 + gl;
        f32x4 gv = *(const f32x4*)&Cs[gl * 132 + jl * 4];
        float r = 1.f / (1.f + expf(-(gv[0] + bb0)));
        float z = 1.f / (1.f + expf(-(gv[1] + bb1)));
        float nn = tanhf(gv[2] + bb2 + r * (gv[3] + bb3));
        float hp = hidCd[(size_t)g * HH + J];
        float hnew = (1.f - z) * nn + z * hp;
        hidNd[(size_t)g * HH + J] = hnew;
        if (l < gcnt[g]) o[(size_t)(starts[g] + l) * HH + J] = hnew;
    }
}

__global__ void fill_sentinel(float* __restrict__ out, float v)
{
    size_t idx = (size_t)blockIdx.x * 256 + threadIdx.x;
    out[idx] = v;
}

// ---------------------------------------------------------------------------
// Workspace layout identical to round 3-6 (verified):
//  W0 h_atom -> outF | W1 bondA.lo -> aggr -> outB | W1h bondA.hi -> x_proj -> msgP
//  W2 bondB.lo -> h/msg | d_out: bondB.hi -> {hid0,hid1,bias4,BgH,BgL} -> final out
// ---------------------------------------------------------------------------
extern "C" void kernel_launch(void* const* d_in, const int* in_sizes, int n_in,
                              void* d_out, int out_size, void* d_ws, size_t ws_size,
                              hipStream_t stream)
{
    (void)in_sizes; (void)n_in; (void)out_size;
    const float* x         = (const float*)d_in[0];
    const float* edge_attr = (const float*)d_in[1];
    const int*   eidx      = (const int*)d_in[2];
    const int*   batch     = (const int*)d_in[3];
    const float* w_atom    = (const float*)d_in[4];
    const float* b_atom    = (const float*)d_in[5];
    const float* w_bond    = (const float*)d_in[6];
    const float* b_bond    = (const float*)d_in[7];
    const float* conv_w    = (const float*)d_in[8];
    const float* conv_b    = (const float*)d_in[9];
    const float* w_lin     = (const float*)d_in[10];
    const float* b_lin     = (const float*)d_in[11];
    const float* gru_bias  = (const float*)d_in[12];
    const float* w_ih      = (const float*)d_in[13];
    const float* w_hh      = (const float*)d_in[14];
    const float* b_ih      = (const float*)d_in[15];
    const float* b_hh      = (const float*)d_in[16];
    const float* w_out     = (const float*)d_in[17];
    const float* b_out     = (const float*)d_in[18];

    const int* row = eidx;
    const int* col = eidx + NEDGES;

    const size_t NH = (size_t)NNODES * HH;

    float* W   = (float*)d_ws;
    float* W0  = W;
    float* W1  = W + NH;
    float* W1h = W + 2 * NH;
    float* W2  = W + 3 * NH;
    float* DO  = (float*)d_out;

    size_t off = 4 * NH;
    int* counts  = (int*)(W + off);      off += NNODES;
    int* cursor  = (int*)(W + off);      off += NNODES;
    int* gcnt    = (int*)(W + off);      off += GG;
    int* starts  = (int*)(W + off);      off += GG;
    int* offsets = (int*)(W + off);      off += NNODES + 1;
    int* elist   = (int*)(W + off);      off += NEDGES;
    float* scX    = W + off;             off += NNODES;
    float* scEA   = W + off;             off += NEDGES;
    float* scHbA  = W + off;             off += NEDGES;
    float* scHbB  = W + off;             off += NEDGES;
    float* scAtom = W + off;             off += NNODES;
    float* scAggr = W + off;             off += NNODES;
    float* scXp   = W + off;             off += NNODES;
    float* scGru  = W + off;             off += GG;
    off = (off + 3) & ~(size_t)3;
    f16* fp = (f16*)(W + off);
    f16* watomH = fp;                     fp += 4 * 256 * 32;
    f16* watomL = fp;                     fp += 4 * 256 * 32;
    f16* wbondH = fp;                     fp += 2 * 256 * 32;
    f16* wbondL = fp;                     fp += 2 * 256 * 32;
    f16* convH[3]; f16* convL[3];
    for (int i = 0; i < 3; i++) { convH[i] = fp; fp += 8 * 256 * 32; convL[i] = fp; fp += 8 * 256 * 32; }
    f16* wlinH = fp;                      fp += 24 * 256 * 32;
    f16* wlinL = fp;                      fp += 24 * 256 * 32;
    f16* woutH = fp;                      fp += 16 * 256 * 32;
    f16* woutL = fp;                      fp += 16 * 256 * 32;

    const size_t NEED = (char*)fp - (char*)d_ws;
    if (ws_size < NEED) {
        fill_sentinel<<<(int)(NH / 256), 256, 0, stream>>>((float*)d_out, (float)ws_size);
        return;
    }

    // d_out overlay (dead between final booster and final GEMM)
    float* hid0  = DO;
    float* hid1  = DO + 2 * (size_t)GG * HH;
    float* bias4 = DO + 4 * (size_t)GG * HH;
    f16* BgH = (f16*)(bias4 + 2048);
    f16* BgL = BgH + (size_t)2 * 16 * 1024 * 32;

    hipMemsetAsync(counts, 0, (size_t)(2 * NNODES + 2 * GG) * sizeof(int), stream);
    prep_graphs<<<(NNODES + 255) / 256, 256, 0, stream>>>(batch, starts, gcnt);
    csr_count<<<(NEDGES + 255) / 256, 256, 0, stream>>>(row, counts);
    scan_offsets<<<1, 1024, 0, stream>>>(counts, offsets);
    csr_fill<<<(NEDGES + 255) / 256, 256, 0, stream>>>(row, offsets, cursor, elist);

    rowscale<<<NNODES, 64, 0, stream>>>(x, 128, scX);
    rowscale<<<NEDGES, 64, 0, stream>>>(edge_attr, 64, scEA);

    prep_wT<<<128, 256, 0, stream>>>(w_atom, watomH, watomL);
    prep_wT<<<64, 256, 0, stream>>>(w_bond, wbondH, wbondL);
    for (int i = 0; i < 3; i++)
        prep_wT<<<256, 256, 0, stream>>>(conv_w + (size_t)i * HH * HH, convH[i], convL[i]);
    prep_wT<<<768, 256, 0, stream>>>(w_lin, wlinH, wlinL);
    prep_wT<<<512, 256, 0, stream>>>(w_out, woutH, woutL);

    // x_proj = relu(x @ w_atom + b_atom) -> W0, scAtom
    gemm_f16x3<0, true, false, true, 3><<<NNODES / 64, 256, 0, stream>>>(
        x, nullptr, nullptr, nullptr, nullptr, nullptr, watomH, watomL, b_atom,
        scX, nullptr, nullptr, W0, nullptr, scAtom, 128);
    // bondA = relu(edge_attr @ w_bond + b_bond) -> (W1, W1h), scHbA
    gemm_f16x3<0, true, true, true, 3><<<NEDGES / 64, 256, 0, stream>>>(
        edge_attr, nullptr, nullptr, nullptr, nullptr, nullptr, wbondH, wbondL, b_bond,
        scEA, nullptr, nullptr, W1, W1h, scHbA, 64);

    float* cur_lo = W1; float* cur_hi = W1h; float* cur_sc = scHbA;
    float* nxt_lo = W2; float* nxt_hi = DO;  float* nxt_sc = scHbB;
    for (int i = 0; i < 3; i++) {
        booster<<<NNODES, 256, 0, stream>>>(cur_lo, cur_hi, W0, W0, offsets, elist, scAtom);
        gemm_f16x3<1, true, true, true, 3><<<NEDGES / 64, 256, 0, stream>>>(
            nullptr, W0, cur_lo, nullptr, row, col, convH[i], convL[i],
            conv_b + (size_t)i * HH, scAtom, cur_sc, nullptr, nxt_lo, nxt_hi, nxt_sc, 256);
        float* t0 = cur_lo; cur_lo = nxt_lo; nxt_lo = t0;
        float* t1 = cur_hi; cur_hi = nxt_hi; nxt_hi = t1;
        float* t2 = cur_sc; cur_sc = nxt_sc; nxt_sc = t2;
    }
    // aggr = h_atom + booster(bondB) -> W1 (bondA dead)
    booster<<<NNODES, 256, 0, stream>>>(cur_lo, cur_hi, W0, W1, offsets, elist, scAggr);
    // recompute x_proj -> W1h
    gemm_f16x3<0, true, false, true, 3><<<NNODES / 64, 256, 0, stream>>>(
        x, nullptr, nullptr, nullptr, nullptr, nullptr, watomH, watomL, b_atom,
        scX, nullptr, nullptr, W1h, nullptr, scXp, 128);
    // h = concat(aggr, h_atom, x_proj) @ w_lin + b_lin -> W2
    gemm_f16x3<2, false, false, false, 3><<<NNODES / 64, 256, 0, stream>>>(
        nullptr, W1, W0, W1h, nullptr, nullptr, wlinH, wlinL, b_lin,
        scAggr, scAtom, scXp, W2, nullptr, nullptr, 768);

    // GRU prep (DO bond rows dead now)
    h0_init<<<GG, 256, 0, stream>>>(W2, starts, gcnt, hid0, scGru);
    build_msgP<<<dim3(LL, GG), 256, 0, stream>>>(W2, gru_bias, starts, gcnt, W1h);
    prep_gruW<<<(2 * 512 * 1024) / 256, 256, 0, stream>>>(w_ih, w_hh, b_ih, b_hh, BgH, BgL, bias4);

    for (int t = 0; t < LL; t++) {
        float* hc = (t & 1) ? hid1 : hid0;
        float* hx = (t & 1) ? hid0 : hid1;
        gru_step_f16<<<512, 256, 0, stream>>>(W1h, BgH, BgL, bias4, hc, hx,
                                              scGru, starts, gcnt, W0, W1, t);
    }

    // out = relu(concat(outF, outB) @ w_out + b_out), pure f16 (NX=1)
    gemm_f16x3<3, true, false, false, 1><<<NNODES / 64, 256, 0, stream>>>(
        nullptr, W0, W1, nullptr, nullptr, batch, woutH, nullptr, b_out,
        scGru, nullptr, nullptr, (float*)d_out, nullptr, nullptr, 512);
}

// Round 10
// 1405.299 us; speedup vs baseline: 1.2089x; 1.0490x over previous
//
#include <hip/hip_runtime.h>
#include <math.h>

#define HH 256
#define GG 1024
#define LL 48
#define NNODES 49152   // G*L
#define NEDGES 98304   // 2*N
#define SB 256.0f      // weight-side scale 2^8
#define DSB 0.00390625f // 2^-8

typedef _Float16 f16;
typedef __attribute__((ext_vector_type(8))) _Float16 f16x8;
typedef __attribute__((ext_vector_type(4))) float f32x4;

#define MFMA16(a, b, c) __builtin_amdgcn_mfma_f32_16x16x32_f16(a, b, c, 0, 0, 0)

__device__ inline float sc_from_max(float m) {
    if (!(m > 0.f)) return 1.0f;
    return ldexpf(1.0f, 13 - ilogbf(m));   // m*sc in [2^13, 2^14)
}

// ---------------------------------------------------------------------------
// CSR build (verified round 2-9)
// ---------------------------------------------------------------------------
__global__ void csr_count(const int* __restrict__ row, int* __restrict__ counts)
{
    int e = blockIdx.x * 256 + threadIdx.x;
    if (e < NEDGES) atomicAdd(&counts[row[e]], 1);
}

__global__ __launch_bounds__(1024) void scan_offsets(const int* __restrict__ counts,
                                                     int* __restrict__ offsets)
{
    __shared__ int tsum[1024];
    const int tid = threadIdx.x;
    const int base = tid * 48;
    int s = 0;
    for (int i = 0; i < 48; i++) s += counts[base + i];
    tsum[tid] = s;
    __syncthreads();
    for (int off = 1; off < 1024; off <<= 1) {
        int v = (tid >= off) ? tsum[tid - off] : 0;
        __syncthreads();
        tsum[tid] += v;
        __syncthreads();
    }
    int run = (tid == 0) ? 0 : tsum[tid - 1];
    for (int i = 0; i < 48; i++) { offsets[base + i] = run; run += counts[base + i]; }
    if (tid == 1023) offsets[NNODES] = run;
}

__global__ void csr_fill(const int* __restrict__ row, const int* __restrict__ offsets,
                         int* __restrict__ cursor, int* __restrict__ elist)
{
    int e = blockIdx.x * 256 + threadIdx.x;
    if (e < NEDGES) {
        int r = row[e];
        int p = atomicAdd(&cursor[r], 1);
        elist[offsets[r] + p] = e;
    }
}

__global__ void prep_graphs(const int* __restrict__ batch, int* __restrict__ starts,
                            int* __restrict__ gcnt)
{
    int i = blockIdx.x * 256 + threadIdx.x;
    if (i < NNODES) {
        int b = batch[i];
        atomicAdd(&gcnt[b], 1);
        if (i == 0 || batch[i - 1] != b) starts[b] = i;
    }
}

__global__ void rowscale(const float* __restrict__ A, int K, float* __restrict__ sc)
{
    int m = blockIdx.x, ln = threadIdx.x;
    float v = 0.f;
    for (int k = ln; k < K; k += 64) v = fmaxf(v, fabsf(A[(size_t)m * K + k]));
    for (int s = 32; s; s >>= 1) v = fmaxf(v, __shfl_xor(v, s));
    if (ln == 0) sc[m] = sc_from_max(v);
}

// merged weight prep: all 7 weight matrices -> blocked transposed f16 hi/lo
// [kblk][256][32], x2^8. krow ranges select the matrix. Bit-identical to the
// per-matrix round-9 prep_wT.
__global__ void prep_wT_all(const float* __restrict__ w_atom, const float* __restrict__ w_bond,
                            const float* __restrict__ conv_w, const float* __restrict__ w_lin,
                            const float* __restrict__ w_out,
                            f16* __restrict__ watomH, f16* __restrict__ watomL,
                            f16* __restrict__ wbondH, f16* __restrict__ wbondL,
                            f16* __restrict__ convH0, f16* __restrict__ convL0,
                            f16* __restrict__ convH1, f16* __restrict__ convL1,
                            f16* __restrict__ convH2, f16* __restrict__ convL2,
                            f16* __restrict__ wlinH, f16* __restrict__ wlinL,
                            f16* __restrict__ woutH, f16* __restrict__ woutL)
{
    int idx = blockIdx.x * 256 + threadIdx.x;
    int krow = idx >> 8, n = idx & 255;
    const float* src; f16* oH; f16* oL; int k;
    if (krow < 128)       { src = w_atom;           oH = watomH; oL = watomL; k = krow; }
    else if (krow < 192)  { src = w_bond;           oH = wbondH; oL = wbondL; k = krow - 128; }
    else if (krow < 448)  { src = conv_w;           oH = convH0; oL = convL0; k = krow - 192; }
    else if (krow < 704)  { src = conv_w + 65536;   oH = convH1; oL = convL1; k = krow - 448; }
    else if (krow < 960)  { src = conv_w + 131072;  oH = convH2; oL = convL2; k = krow - 704; }
    else if (krow < 1728) { src = w_lin;            oH = wlinH;  oL = wlinL;  k = krow - 960; }
    else                  { src = w_out;            oH = woutH;  oL = woutL;  k = krow - 1728; }
    float v = src[(size_t)k * 256 + n] * SB;
    f16 h = (f16)v;
    size_t o = ((size_t)(k >> 5) * 256 + n) * 32 + (k & 31);
    oH[o] = h;
    oL[o] = (f16)(v - (float)h);
}

// GRU weight prep: cols interleaved 4*jj+s; blocked [d][kblk][1024][32] hi/lo
__global__ void prep_gruW(const float* __restrict__ w_ih, const float* __restrict__ w_hh,
                          const float* __restrict__ b_ih, const float* __restrict__ b_hh,
                          f16* __restrict__ BgH, f16* __restrict__ BgL,
                          float* __restrict__ bias4)
{
    int idx = blockIdx.x * 256 + threadIdx.x;   // 2*512*1024
    int d = idx >> 19;
    int rem = idx & 524287;
    int k = rem >> 10;
    int col = rem & 1023;
    int jj = col >> 2, s = col & 3;
    const float* Wi = w_ih + (size_t)d * 768 * 256;
    const float* Wh = w_hh + (size_t)d * 768 * 256;
    float v;
    if (s == 0)      v = (k < 256) ? Wi[(size_t)jj * 256 + k]         : Wh[(size_t)jj * 256 + (k - 256)];
    else if (s == 1) v = (k < 256) ? Wi[(size_t)(256 + jj) * 256 + k] : Wh[(size_t)(256 + jj) * 256 + (k - 256)];
    else if (s == 2) v = (k < 256) ? Wi[(size_t)(512 + jj) * 256 + k] : 0.f;
    else             v = (k < 256) ? 0.f : Wh[(size_t)(512 + jj) * 256 + (k - 256)];
    v *= SB;
    f16 h = (f16)v;
    size_t o = ((size_t)(d * 16 + (k >> 5)) * 1024 + col) * 32 + (k & 31);
    BgH[o] = h;
    BgL[o] = (f16)(v - (float)h);
    if (k == 0) {
        const float* bi = b_ih + d * 768;
        const float* bh = b_hh + d * 768;
        float bv;
        if (s == 0)      bv = bi[jj] + bh[jj];
        else if (s == 1) bv = bi[256 + jj] + bh[256 + jj];
        else if (s == 2) bv = bi[512 + jj];
        else             bv = bh[512 + jj];
        bias4[d * 1024 + col] = bv;
    }
}

// ---------------------------------------------------------------------------
// booster v2: one WAVE per node (4 nodes/block), float4 row loads, shfl-only
// scale reduce. Same per-channel arithmetic order as round-9 (p loop), same
// scale semantics. In-place safe (each lane reads then writes its own quad).
// ---------------------------------------------------------------------------
__global__ void booster(const float* __restrict__ hb_lo, const float* __restrict__ hb_hi,
                        const float* __restrict__ atom_in, float* __restrict__ out,
                        const int* __restrict__ offsets, const int* __restrict__ elist,
                        float* __restrict__ scOut)
{
    const int wv = threadIdx.x >> 6;
    const int n = blockIdx.x * 4 + wv;
    const int ln = threadIdx.x & 63;
    const int b0 = offsets[n], b1 = offsets[n + 1];
    float4 s = {0.f, 0.f, 0.f, 0.f}, m = {0.f, 0.f, 0.f, 0.f};
    for (int p = b0; p < b1; p++) {
        int e = elist[p];
        const float* hb = (e < NNODES) ? (hb_lo + (size_t)e * HH)
                                       : (hb_hi + (size_t)(e - NNODES) * HH);
        float4 v = *(const float4*)(hb + ln * 4);
        s.x += v.x; s.y += v.y; s.z += v.z; s.w += v.w;
        m.x = fmaxf(m.x, v.x); m.y = fmaxf(m.y, v.y);
        m.z = fmaxf(m.z, v.z); m.w = fmaxf(m.w, v.w);
    }
    float4 a = *(const float4*)(atom_in + (size_t)n * HH + ln * 4);
    float4 o;
    o.x = a.x + s.x * m.x; o.y = a.y + s.y * m.y;
    o.z = a.z + s.z * m.z; o.w = a.w + s.w * m.w;
    *(float4*)(out + (size_t)n * HH + ln * 4) = o;
    float v = fmaxf(fmaxf(fabsf(o.x), fabsf(o.y)), fmaxf(fabsf(o.z), fabsf(o.w)));
    for (int t = 32; t; t >>= 1) v = fmaxf(v, __shfl_xor(v, t));
    if (ln == 0) scOut[n] = sc_from_max(v);
}

// h0_init v2: one WAVE per graph (4 graphs/block), float4.
__global__ void h0_init(const float* __restrict__ h, const int* __restrict__ starts,
                        const int* __restrict__ gcnt, float* __restrict__ hid0,
                        float* __restrict__ scG)
{
    const int wv = threadIdx.x >> 6;
    const int g = blockIdx.x * 4 + wv;
    const int ln = threadIdx.x & 63;
    const int st = starts[g], cn = gcnt[g];
    float4 m = {-INFINITY, -INFINITY, -INFINITY, -INFINITY};
    float4 am = {0.f, 0.f, 0.f, 0.f};
    for (int i = 0; i < cn; i++) {
        float4 v = *(const float4*)(h + (size_t)(st + i) * HH + ln * 4);
        m.x = fmaxf(m.x, v.x); m.y = fmaxf(m.y, v.y);
        m.z = fmaxf(m.z, v.z); m.w = fmaxf(m.w, v.w);
        am.x = fmaxf(am.x, fabsf(v.x)); am.y = fmaxf(am.y, fabsf(v.y));
        am.z = fmaxf(am.z, fabsf(v.z)); am.w = fmaxf(am.w, fabsf(v.w));
    }
    if (cn == 0) { m.x = m.y = m.z = m.w = 0.f; }
    *(float4*)(hid0 + (size_t)g * HH + ln * 4) = m;
    *(float4*)(hid0 + (size_t)GG * HH + (size_t)g * HH + ln * 4) = m;
    float a = fmaxf(fmaxf(am.x, am.y), fmaxf(am.z, am.w));
    for (int t = 32; t; t >>= 1) a = fmaxf(a, __shfl_xor(a, t));
    if (ln == 0) scG[g] = sc_from_max(fmaxf(a + 0.07f, 1.0f));
}

// msgP[l][g][k] = relu(h[starts[g]+l][k] + gru_bias[k]) (0 for invalid l)
__global__ void build_msgP(const float* __restrict__ h, const float* __restrict__ gbias,
                           const int* __restrict__ starts, const int* __restrict__ gcnt,
                           float* __restrict__ msgP)
{
    int l = blockIdx.x, g = blockIdx.y, k = threadIdx.x;
    float v = 0.f;
    if (l < gcnt[g]) {
        int node = starts[g] + l;
        v = fmaxf(h[(size_t)node * HH + k] + gbias[k], 0.f);
    }
    msgP[((size_t)l * GG + g) * HH + k] = v;
}

// ---------------------------------------------------------------------------
// A-tile element loaders (8 consecutive k of one row)
// ---------------------------------------------------------------------------
template<int MODE>
__device__ __forceinline__ void gemmLoadA(const float* __restrict__ A,
    const float* __restrict__ S0, const float* __restrict__ S1,
    const float* __restrict__ S2, int rI, int cI, int row, int K, int k,
    float va[8])
{
    if constexpr (MODE == 0) {
        const float* p = A + (size_t)row * K + k;
        float4 v0 = *(const float4*)p, v1 = *(const float4*)(p + 4);
        va[0]=v0.x; va[1]=v0.y; va[2]=v0.z; va[3]=v0.w;
        va[4]=v1.x; va[5]=v1.y; va[6]=v1.z; va[7]=v1.w;
    } else if constexpr (MODE == 1) {
        const float* pa = S0 + (size_t)rI * HH + k;
        const float* pb = S1 + (size_t)cI * HH + k;
        float4 a0 = *(const float4*)pa, a1 = *(const float4*)(pa + 4);
        float4 b0 = *(const float4*)pb, b1 = *(const float4*)(pb + 4);
        va[0]=a0.x-b0.x; va[1]=a0.y-b0.y; va[2]=a0.z-b0.z; va[3]=a0.w-b0.w;
        va[4]=a1.x-b1.x; va[5]=a1.y-b1.y; va[6]=a1.z-b1.z; va[7]=a1.w-b1.w;
    } else if constexpr (MODE == 2) {
        const float* S = (k < 256) ? S0 : ((k < 512) ? S1 : S2);
        const float* p = S + (size_t)row * HH + (k & 255);
        float4 v0 = *(const float4*)p, v1 = *(const float4*)(p + 4);
        va[0]=v0.x; va[1]=v0.y; va[2]=v0.z; va[3]=v0.w;
        va[4]=v1.x; va[5]=v1.y; va[6]=v1.z; va[7]=v1.w;
    } else {
        const float* S = (k < 256) ? S0 : S1;
        const float* p = S + (size_t)row * HH + (k & 255);
        float4 v0 = *(const float4*)p, v1 = *(const float4*)(p + 4);
        va[0]=v0.x; va[1]=v0.y; va[2]=v0.z; va[3]=v0.w;
        va[4]=v1.x; va[5]=v1.y; va[6]=v1.z; va[7]=v1.w;
    }
}

// ---------------------------------------------------------------------------
// f16 split MFMA GEMM with register prefetch — EXACT round-6/9 version
// (verified, w_lin 102 us).
// ---------------------------------------------------------------------------
template<int MODE, bool RELU, bool SPLITC, bool WSCALE, int NX>
__global__ __launch_bounds__(256) void gemm_f16x3(
    const float* __restrict__ A,
    const float* __restrict__ S0, const float* __restrict__ S1, const float* __restrict__ S2,
    const int* __restrict__ ridx, const int* __restrict__ cidx,
    const f16* __restrict__ BgH, const f16* __restrict__ BgL,
    const float* __restrict__ bias,
    const float* __restrict__ sc0, const float* __restrict__ sc1, const float* __restrict__ sc2,
    float* __restrict__ Clo, float* __restrict__ Chi,
    float* __restrict__ scOut, int K)
{
    __shared__ __align__(16) f16 Ah[64 * 40], Al[64 * 40];
    __shared__ __align__(16) f16 Bh[256 * 40], Bl[256 * 40];
    __shared__ float scL[64];
    __shared__ float rmL[64][4];

    const int tid = threadIdx.x;
    const int m0 = blockIdx.x * 64;
    const int arow = tid >> 2, aoct = tid & 3;
    const int w = tid >> 6, lane = tid & 63, lr = lane & 15, lh = lane >> 4;

    if (tid < 64) {
        float sc;
        if constexpr (MODE == 0) sc = sc0[m0 + tid];
        else if constexpr (MODE == 1) {
            int r = ridx[m0 + tid], cc = cidx[m0 + tid];
            sc = fminf(sc0[r], sc1[cc]) * 0.5f;
        } else if constexpr (MODE == 2) {
            sc = fminf(fminf(sc0[m0 + tid], sc1[m0 + tid]), sc2[m0 + tid]);
        } else {
            sc = sc0[cidx[m0 + tid]];
        }
        scL[tid] = sc;
    }
    int rI = 0, cI = 0;
    if constexpr (MODE == 1) { rI = ridx[m0 + arow]; cI = cidx[m0 + arow]; }
    __syncthreads();
    const float myS = scL[arow];

    float va[8];
    f16x8 rbh[4], rbl[4];
    gemmLoadA<MODE>(A, S0, S1, S2, rI, cI, m0 + arow, K, aoct * 8, va);
    {
        size_t base = (size_t)tid * 32;
        const f16x8* ph = (const f16x8*)(BgH + base);
#pragma unroll
        for (int q = 0; q < 4; q++) rbh[q] = ph[q];
        if constexpr (NX == 3) {
            const f16x8* pl = (const f16x8*)(BgL + base);
#pragma unroll
            for (int q = 0; q < 4; q++) rbl[q] = pl[q];
        }
    }

    f32x4 acc[4][4] = {};
    for (int k0 = 0; k0 < K; k0 += 32) {
        {
            f16x8 hi, lo;
#pragma unroll
            for (int e = 0; e < 8; e++) {
                float a = va[e] * myS;
                f16 h = (f16)a;
                hi[e] = h;
                if constexpr (NX == 3) lo[e] = (f16)(a - (float)h);
            }
            *(f16x8*)&Ah[arow * 40 + aoct * 8] = hi;
            if constexpr (NX == 3) *(f16x8*)&Al[arow * 40 + aoct * 8] = lo;
        }
#pragma unroll
        for (int q = 0; q < 4; q++) {
            *(f16x8*)&Bh[tid * 40 + q * 8] = rbh[q];
            if constexpr (NX == 3) *(f16x8*)&Bl[tid * 40 + q * 8] = rbl[q];
        }
        __syncthreads();
        if (k0 + 32 < K) {
            gemmLoadA<MODE>(A, S0, S1, S2, rI, cI, m0 + arow, K, k0 + 32 + aoct * 8, va);
            size_t base = ((size_t)((k0 + 32) >> 5) * 256 + tid) * 32;
            const f16x8* ph = (const f16x8*)(BgH + base);
#pragma unroll
            for (int q = 0; q < 4; q++) rbh[q] = ph[q];
            if constexpr (NX == 3) {
                const f16x8* pl = (const f16x8*)(BgL + base);
#pragma unroll
                for (int q = 0; q < 4; q++) rbl[q] = pl[q];
            }
        }
        f16x8 fah[4], fal[4];
#pragma unroll
        for (int i = 0; i < 4; i++) {
            fah[i] = *(const f16x8*)&Ah[(i * 16 + lr) * 40 + lh * 8];
            if constexpr (NX == 3) fal[i] = *(const f16x8*)&Al[(i * 16 + lr) * 40 + lh * 8];
        }
#pragma unroll
        for (int j = 0; j < 4; j++) {
            int colx = w * 64 + j * 16 + lr;
            f16x8 fbh = *(const f16x8*)&Bh[colx * 40 + lh * 8];
            if constexpr (NX == 3) {
                f16x8 fbl = *(const f16x8*)&Bl[colx * 40 + lh * 8];
#pragma unroll
                for (int i = 0; i < 4; i++) {
                    acc[i][j] = MFMA16(fah[i], fbh, acc[i][j]);
                    acc[i][j] = MFMA16(fah[i], fbl, acc[i][j]);
                    acc[i][j] = MFMA16(fal[i], fbh, acc[i][j]);
                }
            } else {
#pragma unroll
                for (int i = 0; i < 4; i++)
                    acc[i][j] = MFMA16(fah[i], fbh, acc[i][j]);
            }
        }
        __syncthreads();
    }

    float rm[4][4];
#pragma unroll
    for (int i = 0; i < 4; i++)
#pragma unroll
        for (int e = 0; e < 4; e++) rm[i][e] = 0.f;
#pragma unroll
    for (int i = 0; i < 4; i++) {
#pragma unroll
        for (int e = 0; e < 4; e++) {
            int ml = i * 16 + lh * 4 + e;
            int m = m0 + ml;
            float inv = DSB / scL[ml];
            float* Cb;
            if constexpr (SPLITC)
                Cb = (m < NNODES) ? (Clo + (size_t)m * HH) : (Chi + (size_t)(m - NNODES) * HH);
            else
                Cb = Clo + (size_t)m * HH;
#pragma unroll
            for (int j = 0; j < 4; j++) {
                int n = w * 64 + j * 16 + lr;
                float v = acc[i][j][e] * inv + bias[n];
                if constexpr (RELU) v = fmaxf(v, 0.f);
                Cb[n] = v;
                if constexpr (WSCALE) rm[i][e] = fmaxf(rm[i][e], fabsf(v));
            }
        }
    }
    if constexpr (WSCALE) {
#pragma unroll
        for (int i = 0; i < 4; i++)
#pragma unroll
            for (int e = 0; e < 4; e++) {
                float v = rm[i][e];
                v = fmaxf(v, __shfl_xor(v, 1));
                v = fmaxf(v, __shfl_xor(v, 2));
                v = fmaxf(v, __shfl_xor(v, 4));
                v = fmaxf(v, __shfl_xor(v, 8));
                if (lr == 0) rmL[i * 16 + lh * 4 + e][w] = v;
            }
        __syncthreads();
        if (tid < 64)
            scOut[m0 + tid] = sc_from_max(fmaxf(fmaxf(rmL[tid][0], rmL[tid][1]),
                                                fmaxf(rmL[tid][2], rmL[tid][3])));
    }
}

// ---------------------------------------------------------------------------
// GRU step v7: 512-thread blocks, 64 graphs x 128 gate-cols, grid 256
// (8c x 2d x 16gt) -> B L2 traffic halves (64 MB/step). Per-wave tile is
// UNCHANGED vs round 9 (32g x 32c, acc[2][2], same k-order, reg-dbuf B,
// LDS-dbuf A, 1 barrier/window) -> bit-identical numerics.
// ---------------------------------------------------------------------------
__global__ __launch_bounds__(512) void gru_step_f16(
    const float* __restrict__ msgP, const f16* __restrict__ BgH, const f16* __restrict__ BgL,
    const float* __restrict__ bias4, const float* __restrict__ hidC, float* __restrict__ hidN,
    const float* __restrict__ scG, const int* __restrict__ starts, const int* __restrict__ gcnt,
    float* __restrict__ outF, float* __restrict__ outB, int t)
{
    __shared__ __align__(16) char smemraw[36864];   // 2 bufs x (Ah+Al) x 64x72 f16
    float* Cs = (float*)smemraw;                    // union (64*132*4 = 33792B)
    __shared__ float scL[64];

    const int tid = threadIdx.x;
    const int id = blockIdx.x;
    const int c = id & 7, d = (id >> 3) & 1, gt = id >> 4;   // gt 0..15
    const int g0 = gt * 64;
    const int l = d ? (LL - 1 - t) : t;
    const float* hidCd = hidC + (size_t)d * GG * HH;
    float* hidNd = hidN + (size_t)d * GG * HH;

    if (tid < 64) scL[tid] = scG[g0 + tid];
    __syncthreads();

    const int arow = tid >> 3, akoct = tid & 7;   // A: 64 rows x 8 octets (64 k)
    const float myS = scL[arow];
    const int w = tid >> 6;                       // 8 waves
    const int wg = w >> 2, wc = w & 3;            // wave -> (g-half, col-quarter)
    const int lane = tid & 63, lr = lane & 15, lh = lane >> 4;

    f16* Ah0 = (f16*)smemraw;
    f16* Al0 = Ah0 + 4608;
    f16* Ah1 = Al0 + 4608;
    f16* Al1 = Ah1 + 4608;

    // ---- prologue: window 0 A -> buf0; window 0 B -> regs
    {
        const float* p = msgP + ((size_t)l * GG + g0 + arow) * HH + akoct * 8;
        float4 v0 = *(const float4*)p, v1 = *(const float4*)(p + 4);
        float va0[8] = {v0.x, v0.y, v0.z, v0.w, v1.x, v1.y, v1.z, v1.w};
        f16x8 hi, lo;
#pragma unroll
        for (int e = 0; e < 8; e++) {
            float a = va0[e] * myS;
            f16 h = (f16)a;
            hi[e] = h;
            lo[e] = (f16)(a - (float)h);
        }
        *(f16x8*)&Ah0[arow * 72 + akoct * 8] = hi;
        *(f16x8*)&Al0[arow * 72 + akoct * 8] = lo;
    }
    f16x8 fbh[2][2], fbl[2][2];
#pragma unroll
    for (int ks = 0; ks < 2; ks++) {
        size_t kbase = (size_t)(d * 16 + ks) * 1024;
#pragma unroll
        for (int j = 0; j < 2; j++) {
            size_t o = (kbase + (c * 128 + wc * 32 + j * 16 + lr)) * 32 + lh * 8;
            fbh[ks][j] = *(const f16x8*)(BgH + o);
            fbl[ks][j] = *(const f16x8*)(BgL + o);
        }
    }
    __syncthreads();

    f32x4 acc[2][2] = {};
#pragma unroll
    for (int win = 0; win < 8; win++) {
        f16* AhC = (win & 1) ? Ah1 : Ah0;
        f16* AlC = (win & 1) ? Al1 : Al0;
        f16* AhN = (win & 1) ? Ah0 : Ah1;
        f16* AlN = (win & 1) ? Al0 : Al1;

        // issue next-window A loads (global; consumed after MFMA)
        float va[8];
        if (win < 7) {
            int k = (win + 1) * 64 + akoct * 8;
            const float* p = (k < 256)
                ? msgP + ((size_t)l * GG + g0 + arow) * HH + k
                : hidCd + (size_t)(g0 + arow) * HH + (k - 256);
            float4 v0 = *(const float4*)p, v1 = *(const float4*)(p + 4);
            va[0]=v0.x; va[1]=v0.y; va[2]=v0.z; va[3]=v0.w;
            va[4]=v1.x; va[5]=v1.y; va[6]=v1.z; va[7]=v1.w;
        }
        // issue next-window B loads into fresh regs (latency hidden by MFMA)
        f16x8 nbh[2][2], nbl[2][2];
        if (win < 7) {
#pragma unroll
            for (int ks = 0; ks < 2; ks++) {
                size_t kbase = (size_t)(d * 16 + (win + 1) * 2 + ks) * 1024;
#pragma unroll
                for (int j = 0; j < 2; j++) {
                    size_t o = (kbase + (c * 128 + wc * 32 + j * 16 + lr)) * 32 + lh * 8;
                    nbh[ks][j] = *(const f16x8*)(BgH + o);
                    nbl[ks][j] = *(const f16x8*)(BgL + o);
                }
            }
        }
        // MFMA on current window (A from LDS buf, B from regs) — round-6 order
#pragma unroll
        for (int ks = 0; ks < 2; ks++) {
            f16x8 fah[2], fal[2];
#pragma unroll
            for (int i = 0; i < 2; i++) {
                fah[i] = *(const f16x8*)&AhC[(wg * 32 + i * 16 + lr) * 72 + ks * 32 + lh * 8];
                fal[i] = *(const f16x8*)&AlC[(wg * 32 + i * 16 + lr) * 72 + ks * 32 + lh * 8];
            }
#pragma unroll
            for (int j = 0; j < 2; j++) {
#pragma unroll
                for (int i = 0; i < 2; i++) {
                    acc[i][j] = MFMA16(fah[i], fbh[ks][j], acc[i][j]);
                    acc[i][j] = MFMA16(fah[i], fbl[ks][j], acc[i][j]);
                    acc[i][j] = MFMA16(fal[i], fbh[ks][j], acc[i][j]);
                }
            }
        }
        // write next-window A into the other LDS buffer; roll B regs
        if (win < 7) {
            f16x8 hi, lo;
#pragma unroll
            for (int e = 0; e < 8; e++) {
                float a = va[e] * myS;
                f16 h = (f16)a;
                hi[e] = h;
                lo[e] = (f16)(a - (float)h);
            }
            *(f16x8*)&AhN[arow * 72 + akoct * 8] = hi;
            *(f16x8*)&AlN[arow * 72 + akoct * 8] = lo;
#pragma unroll
            for (int ks = 0; ks < 2; ks++)
#pragma unroll
                for (int j = 0; j < 2; j++) {
                    fbh[ks][j] = nbh[ks][j];
                    fbl[ks][j] = nbl[ks][j];
                }
        }
        __syncthreads();
    }

    // stage descaled gate pre-activations: Cs[g_local][col_local], stride 132
#pragma unroll
    for (int i = 0; i < 2; i++) {
#pragma unroll
        for (int e = 0; e < 4; e++) {
            int ml = wg * 32 + i * 16 + lh * 4 + e;
            float inv = DSB / scL[ml];
#pragma unroll
            for (int j = 0; j < 2; j++)
                Cs[ml * 132 + wc * 32 + j * 16 + lr] = acc[i][j][e] * inv;
        }
    }
    __syncthreads();

    // gate epilogue: jj-major mapping for coalesced hid/out stores
    const float* b4 = bias4 + d * 1024;
    const int jl = tid & 31;            // local hidden index (0..31)
    const int J  = c * 32 + jl;         // global hidden index
    const int gbase = (tid >> 5) * 4;   // 4 g per thread (16 groups x 4 = 64)
    const float bb0 = b4[4 * J + 0], bb1 = b4[4 * J + 1];
    const float bb2 = b4[4 * J + 2], bb3 = b4[4 * J + 3];
    float* o = d ? outB : outF;
#pragma unroll
    for (int i = 0; i < 4; i++) {
        int gl = gbase + i;
        int g = g0 + gl;
        f32x4 gv = *(const f32x4*)&Cs[gl * 132 + jl * 4];
        float r = 1.f / (1.f + expf(-(gv[0] + bb0)));
        float z = 1.f / (1.f + expf(-(gv[1] + bb1)));
        float nn = tanhf(gv[2] + bb2 + r * (gv[3] + bb3));
        float hp = hidCd[(size_t)g * HH + J];
        float hnew = (1.f - z) * nn + z * hp;
        hidNd[(size_t)g * HH + J] = hnew;
        if (l < gcnt[g]) o[(size_t)(starts[g] + l) * HH + J] = hnew;
    }
}

__global__ void fill_sentinel(float* __restrict__ out, float v)
{
    size_t idx = (size_t)blockIdx.x * 256 + threadIdx.x;
    out[idx] = v;
}

// ---------------------------------------------------------------------------
// Workspace layout identical to round 3-9 (verified):
//  W0 h_atom -> outF | W1 bondA.lo -> aggr -> outB | W1h bondA.hi -> x_proj -> msgP
//  W2 bondB.lo -> h/msg | d_out: bondB.hi -> {hid0,hid1,bias4,BgH,BgL} -> final out
// ---------------------------------------------------------------------------
extern "C" void kernel_launch(void* const* d_in, const int* in_sizes, int n_in,
                              void* d_out, int out_size, void* d_ws, size_t ws_size,
                              hipStream_t stream)
{
    (void)in_sizes; (void)n_in; (void)out_size;
    const float* x         = (const float*)d_in[0];
    const float* edge_attr = (const float*)d_in[1];
    const int*   eidx      = (const int*)d_in[2];
    const int*   batch     = (const int*)d_in[3];
    const float* w_atom    = (const float*)d_in[4];
    const float* b_atom    = (const float*)d_in[5];
    const float* w_bond    = (const float*)d_in[6];
    const float* b_bond    = (const float*)d_in[7];
    const float* conv_w    = (const float*)d_in[8];
    const float* conv_b    = (const float*)d_in[9];
    const float* w_lin     = (const float*)d_in[10];
    const float* b_lin     = (const float*)d_in[11];
    const float* gru_bias  = (const float*)d_in[12];
    const float* w_ih      = (const float*)d_in[13];
    const float* w_hh      = (const float*)d_in[14];
    const float* b_ih      = (const float*)d_in[15];
    const float* b_hh      = (const float*)d_in[16];
    const float* w_out     = (const float*)d_in[17];
    const float* b_out     = (const float*)d_in[18];

    const int* row = eidx;
    const int* col = eidx + NEDGES;

    const size_t NH = (size_t)NNODES * HH;

    float* W   = (float*)d_ws;
    float* W0  = W;
    float* W1  = W + NH;
    float* W1h = W + 2 * NH;
    float* W2  = W + 3 * NH;
    float* DO  = (float*)d_out;

    size_t off = 4 * NH;
    int* counts  = (int*)(W + off);      off += NNODES;
    int* cursor  = (int*)(W + off);      off += NNODES;
    int* gcnt    = (int*)(W + off);      off += GG;
    int* starts  = (int*)(W + off);      off += GG;
    int* offsets = (int*)(W + off);      off += NNODES + 1;
    int* elist   = (int*)(W + off);      off += NEDGES;
    float* scX    = W + off;             off += NNODES;
    float* scEA   = W + off;             off += NEDGES;
    float* scHbA  = W + off;             off += NEDGES;
    float* scHbB  = W + off;             off += NEDGES;
    float* scAtom = W + off;             off += NNODES;
    float* scAggr = W + off;             off += NNODES;
    float* scXp   = W + off;             off += NNODES;
    float* scGru  = W + off;             off += GG;
    off = (off + 3) & ~(size_t)3;
    f16* fp = (f16*)(W + off);
    f16* watomH = fp;                     fp += 4 * 256 * 32;
    f16* watomL = fp;                     fp += 4 * 256 * 32;
    f16* wbondH = fp;                     fp += 2 * 256 * 32;
    f16* wbondL = fp;                     fp += 2 * 256 * 32;
    f16* convH[3]; f16* convL[3];
    for (int i = 0; i < 3; i++) { convH[i] = fp; fp += 8 * 256 * 32; convL[i] = fp; fp += 8 * 256 * 32; }
    f16* wlinH = fp;                      fp += 24 * 256 * 32;
    f16* wlinL = fp;                      fp += 24 * 256 * 32;
    f16* woutH = fp;                      fp += 16 * 256 * 32;
    f16* woutL = fp;                      fp += 16 * 256 * 32;

    const size_t NEED = (char*)fp - (char*)d_ws;
    if (ws_size < NEED) {
        fill_sentinel<<<(int)(NH / 256), 256, 0, stream>>>((float*)d_out, (float)ws_size);
        return;
    }

    // d_out overlay (dead between final booster and final GEMM)
    float* hid0  = DO;
    float* hid1  = DO + 2 * (size_t)GG * HH;
    float* bias4 = DO + 4 * (size_t)GG * HH;
    f16* BgH = (f16*)(bias4 + 2048);
    f16* BgL = BgH + (size_t)2 * 16 * 1024 * 32;

    hipMemsetAsync(counts, 0, (size_t)(2 * NNODES + 2 * GG) * sizeof(int), stream);
    prep_graphs<<<(NNODES + 255) / 256, 256, 0, stream>>>(batch, starts, gcnt);
    csr_count<<<(NEDGES + 255) / 256, 256, 0, stream>>>(row, counts);
    scan_offsets<<<1, 1024, 0, stream>>>(counts, offsets);
    csr_fill<<<(NEDGES + 255) / 256, 256, 0, stream>>>(row, offsets, cursor, elist);

    rowscale<<<NNODES, 64, 0, stream>>>(x, 128, scX);
    rowscale<<<NEDGES, 64, 0, stream>>>(edge_attr, 64, scEA);

    prep_wT_all<<<2240, 256, 0, stream>>>(w_atom, w_bond, conv_w, w_lin, w_out,
        watomH, watomL, wbondH, wbondL, convH[0], convL[0], convH[1], convL[1],
        convH[2], convL[2], wlinH, wlinL, woutH, woutL);

    // x_proj = relu(x @ w_atom + b_atom) -> W0, scAtom
    gemm_f16x3<0, true, false, true, 3><<<NNODES / 64, 256, 0, stream>>>(
        x, nullptr, nullptr, nullptr, nullptr, nullptr, watomH, watomL, b_atom,
        scX, nullptr, nullptr, W0, nullptr, scAtom, 128);
    // bondA = relu(edge_attr @ w_bond + b_bond) -> (W1, W1h), scHbA
    gemm_f16x3<0, true, true, true, 3><<<NEDGES / 64, 256, 0, stream>>>(
        edge_attr, nullptr, nullptr, nullptr, nullptr, nullptr, wbondH, wbondL, b_bond,
        scEA, nullptr, nullptr, W1, W1h, scHbA, 64);

    float* cur_lo = W1; float* cur_hi = W1h; float* cur_sc = scHbA;
    float* nxt_lo = W2; float* nxt_hi = DO;  float* nxt_sc = scHbB;
    for (int i = 0; i < 3; i++) {
        booster<<<NNODES / 4, 256, 0, stream>>>(cur_lo, cur_hi, W0, W0, offsets, elist, scAtom);
        gemm_f16x3<1, true, true, true, 3><<<NEDGES / 64, 256, 0, stream>>>(
            nullptr, W0, cur_lo, nullptr, row, col, convH[i], convL[i],
            conv_b + (size_t)i * HH, scAtom, cur_sc, nullptr, nxt_lo, nxt_hi, nxt_sc, 256);
        float* t0 = cur_lo; cur_lo = nxt_lo; nxt_lo = t0;
        float* t1 = cur_hi; cur_hi = nxt_hi; nxt_hi = t1;
        float* t2 = cur_sc; cur_sc = nxt_sc; nxt_sc = t2;
    }
    // aggr = h_atom + booster(bondB) -> W1 (bondA dead)
    booster<<<NNODES / 4, 256, 0, stream>>>(cur_lo, cur_hi, W0, W1, offsets, elist, scAggr);
    // recompute x_proj -> W1h
    gemm_f16x3<0, true, false, true, 3><<<NNODES / 64, 256, 0, stream>>>(
        x, nullptr, nullptr, nullptr, nullptr, nullptr, watomH, watomL, b_atom,
        scX, nullptr, nullptr, W1h, nullptr, scXp, 128);
    // h = concat(aggr, h_atom, x_proj) @ w_lin + b_lin -> W2
    gemm_f16x3<2, false, false, false, 3><<<NNODES / 64, 256, 0, stream>>>(
        nullptr, W1, W0, W1h, nullptr, nullptr, wlinH, wlinL, b_lin,
        scAggr, scAtom, scXp, W2, nullptr, nullptr, 768);

    // GRU prep (DO bond rows dead now)
    h0_init<<<GG / 4, 256, 0, stream>>>(W2, starts, gcnt, hid0, scGru);
    build_msgP<<<dim3(LL, GG), 256, 0, stream>>>(W2, gru_bias, starts, gcnt, W1h);
    prep_gruW<<<(2 * 512 * 1024) / 256, 256, 0, stream>>>(w_ih, w_hh, b_ih, b_hh, BgH, BgL, bias4);

    for (int t = 0; t < LL; t++) {
        float* hc = (t & 1) ? hid1 : hid0;
        float* hx = (t & 1) ? hid0 : hid1;
        gru_step_f16<<<256, 512, 0, stream>>>(W1h, BgH, BgL, bias4, hc, hx,
                                              scGru, starts, gcnt, W0, W1, t);
    }

    // out = relu(concat(outF, outB) @ w_out + b_out), pure f16 (NX=1)
    gemm_f16x3<3, true, false, false, 1><<<NNODES / 64, 256, 0, stream>>>(
        nullptr, W0, W1, nullptr, nullptr, batch, woutH, nullptr, b_out,
        scGru, nullptr, nullptr, (float*)d_out, nullptr, nullptr, 512);
}

// Round 11
// 1397.489 us; speedup vs baseline: 1.2157x; 1.0056x over previous
//
#include <hip/hip_runtime.h>
#include <math.h>

#define HH 256
#define GG 1024
#define LL 48
#define NNODES 49152   // G*L
#define NEDGES 98304   // 2*N
#define SB 256.0f      // weight-side scale 2^8
#define DSB 0.00390625f // 2^-8

typedef _Float16 f16;
typedef __attribute__((ext_vector_type(8))) _Float16 f16x8;
typedef __attribute__((ext_vector_type(4))) float f32x4;

#define MFMA16(a, b, c) __builtin_amdgcn_mfma_f32_16x16x32_f16(a, b, c, 0, 0, 0)

__device__ inline float sc_from_max(float m) {
    if (!(m > 0.f)) return 1.0f;
    return ldexpf(1.0f, 13 - ilogbf(m));   // m*sc in [2^13, 2^14)
}

// ---------------------------------------------------------------------------
// CSR build (verified round 2-10)
// ---------------------------------------------------------------------------
__global__ void csr_count(const int* __restrict__ row, int* __restrict__ counts)
{
    int e = blockIdx.x * 256 + threadIdx.x;
    if (e < NEDGES) atomicAdd(&counts[row[e]], 1);
}

__global__ __launch_bounds__(1024) void scan_offsets(const int* __restrict__ counts,
                                                     int* __restrict__ offsets)
{
    __shared__ int tsum[1024];
    const int tid = threadIdx.x;
    const int base = tid * 48;
    int s = 0;
    for (int i = 0; i < 48; i++) s += counts[base + i];
    tsum[tid] = s;
    __syncthreads();
    for (int off = 1; off < 1024; off <<= 1) {
        int v = (tid >= off) ? tsum[tid - off] : 0;
        __syncthreads();
        tsum[tid] += v;
        __syncthreads();
    }
    int run = (tid == 0) ? 0 : tsum[tid - 1];
    for (int i = 0; i < 48; i++) { offsets[base + i] = run; run += counts[base + i]; }
    if (tid == 1023) offsets[NNODES] = run;
}

__global__ void csr_fill(const int* __restrict__ row, const int* __restrict__ offsets,
                         int* __restrict__ cursor, int* __restrict__ elist)
{
    int e = blockIdx.x * 256 + threadIdx.x;
    if (e < NEDGES) {
        int r = row[e];
        int p = atomicAdd(&cursor[r], 1);
        elist[offsets[r] + p] = e;
    }
}

__global__ void prep_graphs(const int* __restrict__ batch, int* __restrict__ starts,
                            int* __restrict__ gcnt)
{
    int i = blockIdx.x * 256 + threadIdx.x;
    if (i < NNODES) {
        int b = batch[i];
        atomicAdd(&gcnt[b], 1);
        if (i == 0 || batch[i - 1] != b) starts[b] = i;
    }
}

__global__ void rowscale(const float* __restrict__ A, int K, float* __restrict__ sc)
{
    int m = blockIdx.x, ln = threadIdx.x;
    float v = 0.f;
    for (int k = ln; k < K; k += 64) v = fmaxf(v, fabsf(A[(size_t)m * K + k]));
    for (int s = 32; s; s >>= 1) v = fmaxf(v, __shfl_xor(v, s));
    if (ln == 0) sc[m] = sc_from_max(v);
}

// merged weight prep (verified round 10)
__global__ void prep_wT_all(const float* __restrict__ w_atom, const float* __restrict__ w_bond,
                            const float* __restrict__ conv_w, const float* __restrict__ w_lin,
                            const float* __restrict__ w_out,
                            f16* __restrict__ watomH, f16* __restrict__ watomL,
                            f16* __restrict__ wbondH, f16* __restrict__ wbondL,
                            f16* __restrict__ convH0, f16* __restrict__ convL0,
                            f16* __restrict__ convH1, f16* __restrict__ convL1,
                            f16* __restrict__ convH2, f16* __restrict__ convL2,
                            f16* __restrict__ wlinH, f16* __restrict__ wlinL,
                            f16* __restrict__ woutH, f16* __restrict__ woutL)
{
    int idx = blockIdx.x * 256 + threadIdx.x;
    int krow = idx >> 8, n = idx & 255;
    const float* src; f16* oH; f16* oL; int k;
    if (krow < 128)       { src = w_atom;           oH = watomH; oL = watomL; k = krow; }
    else if (krow < 192)  { src = w_bond;           oH = wbondH; oL = wbondL; k = krow - 128; }
    else if (krow < 448)  { src = conv_w;           oH = convH0; oL = convL0; k = krow - 192; }
    else if (krow < 704)  { src = conv_w + 65536;   oH = convH1; oL = convL1; k = krow - 448; }
    else if (krow < 960)  { src = conv_w + 131072;  oH = convH2; oL = convL2; k = krow - 704; }
    else if (krow < 1728) { src = w_lin;            oH = wlinH;  oL = wlinL;  k = krow - 960; }
    else                  { src = w_out;            oH = woutH;  oL = woutL;  k = krow - 1728; }
    float v = src[(size_t)k * 256 + n] * SB;
    f16 h = (f16)v;
    size_t o = ((size_t)(k >> 5) * 256 + n) * 32 + (k & 31);
    oH[o] = h;
    oL[o] = (f16)(v - (float)h);
}

// GRU weight prep (verified round 2-10)
__global__ void prep_gruW(const float* __restrict__ w_ih, const float* __restrict__ w_hh,
                          const float* __restrict__ b_ih, const float* __restrict__ b_hh,
                          f16* __restrict__ BgH, f16* __restrict__ BgL,
                          float* __restrict__ bias4)
{
    int idx = blockIdx.x * 256 + threadIdx.x;   // 2*512*1024
    int d = idx >> 19;
    int rem = idx & 524287;
    int k = rem >> 10;
    int col = rem & 1023;
    int jj = col >> 2, s = col & 3;
    const float* Wi = w_ih + (size_t)d * 768 * 256;
    const float* Wh = w_hh + (size_t)d * 768 * 256;
    float v;
    if (s == 0)      v = (k < 256) ? Wi[(size_t)jj * 256 + k]         : Wh[(size_t)jj * 256 + (k - 256)];
    else if (s == 1) v = (k < 256) ? Wi[(size_t)(256 + jj) * 256 + k] : Wh[(size_t)(256 + jj) * 256 + (k - 256)];
    else if (s == 2) v = (k < 256) ? Wi[(size_t)(512 + jj) * 256 + k] : 0.f;
    else             v = (k < 256) ? 0.f : Wh[(size_t)(512 + jj) * 256 + (k - 256)];
    v *= SB;
    f16 h = (f16)v;
    size_t o = ((size_t)(d * 16 + (k >> 5)) * 1024 + col) * 32 + (k & 31);
    BgH[o] = h;
    BgL[o] = (f16)(v - (float)h);
    if (k == 0) {
        const float* bi = b_ih + d * 768;
        const float* bh = b_hh + d * 768;
        float bv;
        if (s == 0)      bv = bi[jj] + bh[jj];
        else if (s == 1) bv = bi[256 + jj] + bh[256 + jj];
        else if (s == 2) bv = bi[512 + jj];
        else             bv = bh[512 + jj];
        bias4[d * 1024 + col] = bv;
    }
}

// booster v2 (verified round 10): one WAVE per node, float4, shfl reduce
__global__ void booster(const float* __restrict__ hb_lo, const float* __restrict__ hb_hi,
                        const float* __restrict__ atom_in, float* __restrict__ out,
                        const int* __restrict__ offsets, const int* __restrict__ elist,
                        float* __restrict__ scOut)
{
    const int wv = threadIdx.x >> 6;
    const int n = blockIdx.x * 4 + wv;
    const int ln = threadIdx.x & 63;
    const int b0 = offsets[n], b1 = offsets[n + 1];
    float4 s = {0.f, 0.f, 0.f, 0.f}, m = {0.f, 0.f, 0.f, 0.f};
    for (int p = b0; p < b1; p++) {
        int e = elist[p];
        const float* hb = (e < NNODES) ? (hb_lo + (size_t)e * HH)
                                       : (hb_hi + (size_t)(e - NNODES) * HH);
        float4 v = *(const float4*)(hb + ln * 4);
        s.x += v.x; s.y += v.y; s.z += v.z; s.w += v.w;
        m.x = fmaxf(m.x, v.x); m.y = fmaxf(m.y, v.y);
        m.z = fmaxf(m.z, v.z); m.w = fmaxf(m.w, v.w);
    }
    float4 a = *(const float4*)(atom_in + (size_t)n * HH + ln * 4);
    float4 o;
    o.x = a.x + s.x * m.x; o.y = a.y + s.y * m.y;
    o.z = a.z + s.z * m.z; o.w = a.w + s.w * m.w;
    *(float4*)(out + (size_t)n * HH + ln * 4) = o;
    float v = fmaxf(fmaxf(fabsf(o.x), fabsf(o.y)), fmaxf(fabsf(o.z), fabsf(o.w)));
    for (int t = 32; t; t >>= 1) v = fmaxf(v, __shfl_xor(v, t));
    if (ln == 0) scOut[n] = sc_from_max(v);
}

// h0_init v2 (verified round 10)
__global__ void h0_init(const float* __restrict__ h, const int* __restrict__ starts,
                        const int* __restrict__ gcnt, float* __restrict__ hid0,
                        float* __restrict__ scG)
{
    const int wv = threadIdx.x >> 6;
    const int g = blockIdx.x * 4 + wv;
    const int ln = threadIdx.x & 63;
    const int st = starts[g], cn = gcnt[g];
    float4 m = {-INFINITY, -INFINITY, -INFINITY, -INFINITY};
    float4 am = {0.f, 0.f, 0.f, 0.f};
    for (int i = 0; i < cn; i++) {
        float4 v = *(const float4*)(h + (size_t)(st + i) * HH + ln * 4);
        m.x = fmaxf(m.x, v.x); m.y = fmaxf(m.y, v.y);
        m.z = fmaxf(m.z, v.z); m.w = fmaxf(m.w, v.w);
        am.x = fmaxf(am.x, fabsf(v.x)); am.y = fmaxf(am.y, fabsf(v.y));
        am.z = fmaxf(am.z, fabsf(v.z)); am.w = fmaxf(am.w, fabsf(v.w));
    }
    if (cn == 0) { m.x = m.y = m.z = m.w = 0.f; }
    *(float4*)(hid0 + (size_t)g * HH + ln * 4) = m;
    *(float4*)(hid0 + (size_t)GG * HH + (size_t)g * HH + ln * 4) = m;
    float a = fmaxf(fmaxf(am.x, am.y), fmaxf(am.z, am.w));
    for (int t = 32; t; t >>= 1) a = fmaxf(a, __shfl_xor(a, t));
    if (ln == 0) scG[g] = sc_from_max(fmaxf(a + 0.07f, 1.0f));
}

// msgP[l][g][k] = relu(h[starts[g]+l][k] + gru_bias[k]) (0 for invalid l)
__global__ void build_msgP(const float* __restrict__ h, const float* __restrict__ gbias,
                           const int* __restrict__ starts, const int* __restrict__ gcnt,
                           float* __restrict__ msgP)
{
    int l = blockIdx.x, g = blockIdx.y, k = threadIdx.x;
    float v = 0.f;
    if (l < gcnt[g]) {
        int node = starts[g] + l;
        v = fmaxf(h[(size_t)node * HH + k] + gbias[k], 0.f);
    }
    msgP[((size_t)l * GG + g) * HH + k] = v;
}

// ---------------------------------------------------------------------------
// A-tile element loaders (8 consecutive k of one row)
// ---------------------------------------------------------------------------
template<int MODE>
__device__ __forceinline__ void gemmLoadA(const float* __restrict__ A,
    const float* __restrict__ S0, const float* __restrict__ S1,
    const float* __restrict__ S2, int rI, int cI, int row, int K, int k,
    float va[8])
{
    if constexpr (MODE == 0) {
        const float* p = A + (size_t)row * K + k;
        float4 v0 = *(const float4*)p, v1 = *(const float4*)(p + 4);
        va[0]=v0.x; va[1]=v0.y; va[2]=v0.z; va[3]=v0.w;
        va[4]=v1.x; va[5]=v1.y; va[6]=v1.z; va[7]=v1.w;
    } else if constexpr (MODE == 1) {
        const float* pa = S0 + (size_t)rI * HH + k;
        const float* pb = S1 + (size_t)cI * HH + k;
        float4 a0 = *(const float4*)pa, a1 = *(const float4*)(pa + 4);
        float4 b0 = *(const float4*)pb, b1 = *(const float4*)(pb + 4);
        va[0]=a0.x-b0.x; va[1]=a0.y-b0.y; va[2]=a0.z-b0.z; va[3]=a0.w-b0.w;
        va[4]=a1.x-b1.x; va[5]=a1.y-b1.y; va[6]=a1.z-b1.z; va[7]=a1.w-b1.w;
    } else if constexpr (MODE == 2) {
        const float* S = (k < 256) ? S0 : ((k < 512) ? S1 : S2);
        const float* p = S + (size_t)row * HH + (k & 255);
        float4 v0 = *(const float4*)p, v1 = *(const float4*)(p + 4);
        va[0]=v0.x; va[1]=v0.y; va[2]=v0.z; va[3]=v0.w;
        va[4]=v1.x; va[5]=v1.y; va[6]=v1.z; va[7]=v1.w;
    } else {
        const float* S = (k < 256) ? S0 : S1;
        const float* p = S + (size_t)row * HH + (k & 255);
        float4 v0 = *(const float4*)p, v1 = *(const float4*)(p + 4);
        va[0]=v0.x; va[1]=v0.y; va[2]=v0.z; va[3]=v0.w;
        va[4]=v1.x; va[5]=v1.y; va[6]=v1.z; va[7]=v1.w;
    }
}

// ---------------------------------------------------------------------------
// f16 split MFMA GEMM v3 (GRU-v6 schedule): A-LDS double-buffered, B direct
// from global into a register double-buffer, ONE barrier per k-iteration.
// Per-acc MFMA operand order identical to round 6/9/10 -> bit-identical.
// ---------------------------------------------------------------------------
template<int MODE, bool RELU, bool SPLITC, bool WSCALE, int NX>
__global__ __launch_bounds__(256, 2) void gemm_f16x3(
    const float* __restrict__ A,
    const float* __restrict__ S0, const float* __restrict__ S1, const float* __restrict__ S2,
    const int* __restrict__ ridx, const int* __restrict__ cidx,
    const f16* __restrict__ BgH, const f16* __restrict__ BgL,
    const float* __restrict__ bias,
    const float* __restrict__ sc0, const float* __restrict__ sc1, const float* __restrict__ sc2,
    float* __restrict__ Clo, float* __restrict__ Chi,
    float* __restrict__ scOut, int K)
{
    __shared__ __align__(16) f16 AhB[2][64 * 40], AlB[2][64 * 40];
    __shared__ float scL[64];
    __shared__ float rmL[64][4];

    const int tid = threadIdx.x;
    const int m0 = blockIdx.x * 64;
    const int arow = tid >> 2, aoct = tid & 3;
    const int w = tid >> 6, lane = tid & 63, lr = lane & 15, lh = lane >> 4;

    if (tid < 64) {
        float sc;
        if constexpr (MODE == 0) sc = sc0[m0 + tid];
        else if constexpr (MODE == 1) {
            int r = ridx[m0 + tid], cc = cidx[m0 + tid];
            sc = fminf(sc0[r], sc1[cc]) * 0.5f;
        } else if constexpr (MODE == 2) {
            sc = fminf(fminf(sc0[m0 + tid], sc1[m0 + tid]), sc2[m0 + tid]);
        } else {
            sc = sc0[cidx[m0 + tid]];
        }
        scL[tid] = sc;
    }
    int rI = 0, cI = 0;
    if constexpr (MODE == 1) { rI = ridx[m0 + arow]; cI = cidx[m0 + arow]; }
    __syncthreads();
    const float myS = scL[arow];
    const int nIter = K >> 5;

    // ---- prologue: iter 0 A -> LDS buf0; iter 0 B -> regs
    {
        float va0[8];
        gemmLoadA<MODE>(A, S0, S1, S2, rI, cI, m0 + arow, K, aoct * 8, va0);
        f16x8 hi, lo;
#pragma unroll
        for (int e = 0; e < 8; e++) {
            float a = va0[e] * myS;
            f16 h = (f16)a;
            hi[e] = h;
            if constexpr (NX == 3) lo[e] = (f16)(a - (float)h);
        }
        *(f16x8*)&AhB[0][arow * 40 + aoct * 8] = hi;
        if constexpr (NX == 3) *(f16x8*)&AlB[0][arow * 40 + aoct * 8] = lo;
    }
    f16x8 fbh[4], fbl[4];
#pragma unroll
    for (int j = 0; j < 4; j++) {
        size_t o = (size_t)(w * 64 + j * 16 + lr) * 32 + lh * 8;
        fbh[j] = *(const f16x8*)(BgH + o);
        if constexpr (NX == 3) fbl[j] = *(const f16x8*)(BgL + o);
    }
    __syncthreads();

    f32x4 acc[4][4] = {};
    for (int kb = 0; kb < nIter; kb++) {
        const f16* AhC = AhB[kb & 1];
        const f16* AlC = AlB[kb & 1];
        // issue next-iter A loads (global) and B loads (global, fresh regs)
        float va[8];
        f16x8 nbh[4], nbl[4];
        if (kb + 1 < nIter) {
            gemmLoadA<MODE>(A, S0, S1, S2, rI, cI, m0 + arow, K, (kb + 1) * 32 + aoct * 8, va);
#pragma unroll
            for (int j = 0; j < 4; j++) {
                size_t o = ((size_t)(kb + 1) * 256 + (w * 64 + j * 16 + lr)) * 32 + lh * 8;
                nbh[j] = *(const f16x8*)(BgH + o);
                if constexpr (NX == 3) nbl[j] = *(const f16x8*)(BgL + o);
            }
        }
        // MFMA on current iter (A from LDS, B from regs) — round-6 order
        f16x8 fah[4], fal[4];
#pragma unroll
        for (int i = 0; i < 4; i++) {
            fah[i] = *(const f16x8*)&AhC[(i * 16 + lr) * 40 + lh * 8];
            if constexpr (NX == 3) fal[i] = *(const f16x8*)&AlC[(i * 16 + lr) * 40 + lh * 8];
        }
#pragma unroll
        for (int j = 0; j < 4; j++) {
            if constexpr (NX == 3) {
#pragma unroll
                for (int i = 0; i < 4; i++) {
                    acc[i][j] = MFMA16(fah[i], fbh[j], acc[i][j]);
                    acc[i][j] = MFMA16(fah[i], fbl[j], acc[i][j]);
                    acc[i][j] = MFMA16(fal[i], fbh[j], acc[i][j]);
                }
            } else {
#pragma unroll
                for (int i = 0; i < 4; i++)
                    acc[i][j] = MFMA16(fah[i], fbh[j], acc[i][j]);
            }
        }
        // write next A into the other LDS buffer; roll B regs
        if (kb + 1 < nIter) {
            f16x8 hi, lo;
#pragma unroll
            for (int e = 0; e < 8; e++) {
                float a = va[e] * myS;
                f16 h = (f16)a;
                hi[e] = h;
                if constexpr (NX == 3) lo[e] = (f16)(a - (float)h);
            }
            f16* AhN = AhB[(kb + 1) & 1];
            f16* AlN = AlB[(kb + 1) & 1];
            *(f16x8*)&AhN[arow * 40 + aoct * 8] = hi;
            if constexpr (NX == 3) *(f16x8*)&AlN[arow * 40 + aoct * 8] = lo;
#pragma unroll
            for (int j = 0; j < 4; j++) {
                fbh[j] = nbh[j];
                if constexpr (NX == 3) fbl[j] = nbl[j];
            }
        }
        __syncthreads();
    }

    float rm[4][4];
#pragma unroll
    for (int i = 0; i < 4; i++)
#pragma unroll
        for (int e = 0; e < 4; e++) rm[i][e] = 0.f;
#pragma unroll
    for (int i = 0; i < 4; i++) {
#pragma unroll
        for (int e = 0; e < 4; e++) {
            int ml = i * 16 + lh * 4 + e;
            int m = m0 + ml;
            float inv = DSB / scL[ml];
            float* Cb;
            if constexpr (SPLITC)
                Cb = (m < NNODES) ? (Clo + (size_t)m * HH) : (Chi + (size_t)(m - NNODES) * HH);
            else
                Cb = Clo + (size_t)m * HH;
#pragma unroll
            for (int j = 0; j < 4; j++) {
                int n = w * 64 + j * 16 + lr;
                float v = acc[i][j][e] * inv + bias[n];
                if constexpr (RELU) v = fmaxf(v, 0.f);
                Cb[n] = v;
                if constexpr (WSCALE) rm[i][e] = fmaxf(rm[i][e], fabsf(v));
            }
        }
    }
    if constexpr (WSCALE) {
#pragma unroll
        for (int i = 0; i < 4; i++)
#pragma unroll
            for (int e = 0; e < 4; e++) {
                float v = rm[i][e];
                v = fmaxf(v, __shfl_xor(v, 1));
                v = fmaxf(v, __shfl_xor(v, 2));
                v = fmaxf(v, __shfl_xor(v, 4));
                v = fmaxf(v, __shfl_xor(v, 8));
                if (lr == 0) rmL[i * 16 + lh * 4 + e][w] = v;
            }
        __syncthreads();
        if (tid < 64)
            scOut[m0 + tid] = sc_from_max(fmaxf(fmaxf(rmL[tid][0], rmL[tid][1]),
                                                fmaxf(rmL[tid][2], rmL[tid][3])));
    }
}

// ---------------------------------------------------------------------------
// GRU step v7 (verified round 10): 512 threads, 64g x 128c, grid 256,
// reg-dbuf B + LDS-dbuf A + 1 barrier/window. Bit-identical numerics.
// ---------------------------------------------------------------------------
__global__ __launch_bounds__(512) void gru_step_f16(
    const float* __restrict__ msgP, const f16* __restrict__ BgH, const f16* __restrict__ BgL,
    const float* __restrict__ bias4, const float* __restrict__ hidC, float* __restrict__ hidN,
    const float* __restrict__ scG, const int* __restrict__ starts, const int* __restrict__ gcnt,
    float* __restrict__ outF, float* __restrict__ outB, int t)
{
    __shared__ __align__(16) char smemraw[36864];
    float* Cs = (float*)smemraw;
    __shared__ float scL[64];

    const int tid = threadIdx.x;
    const int id = blockIdx.x;
    const int c = id & 7, d = (id >> 3) & 1, gt = id >> 4;
    const int g0 = gt * 64;
    const int l = d ? (LL - 1 - t) : t;
    const float* hidCd = hidC + (size_t)d * GG * HH;
    float* hidNd = hidN + (size_t)d * GG * HH;

    if (tid < 64) scL[tid] = scG[g0 + tid];
    __syncthreads();

    const int arow = tid >> 3, akoct = tid & 7;
    const float myS = scL[arow];
    const int w = tid >> 6;
    const int wg = w >> 2, wc = w & 3;
    const int lane = tid & 63, lr = lane & 15, lh = lane >> 4;

    f16* Ah0 = (f16*)smemraw;
    f16* Al0 = Ah0 + 4608;
    f16* Ah1 = Al0 + 4608;
    f16* Al1 = Ah1 + 4608;

    {
        const float* p = msgP + ((size_t)l * GG + g0 + arow) * HH + akoct * 8;
        float4 v0 = *(const float4*)p, v1 = *(const float4*)(p + 4);
        float va0[8] = {v0.x, v0.y, v0.z, v0.w, v1.x, v1.y, v1.z, v1.w};
        f16x8 hi, lo;
#pragma unroll
        for (int e = 0; e < 8; e++) {
            float a = va0[e] * myS;
            f16 h = (f16)a;
            hi[e] = h;
            lo[e] = (f16)(a - (float)h);
        }
        *(f16x8*)&Ah0[arow * 72 + akoct * 8] = hi;
        *(f16x8*)&Al0[arow * 72 + akoct * 8] = lo;
    }
    f16x8 fbh[2][2], fbl[2][2];
#pragma unroll
    for (int ks = 0; ks < 2; ks++) {
        size_t kbase = (size_t)(d * 16 + ks) * 1024;
#pragma unroll
        for (int j = 0; j < 2; j++) {
            size_t o = (kbase + (c * 128 + wc * 32 + j * 16 + lr)) * 32 + lh * 8;
            fbh[ks][j] = *(const f16x8*)(BgH + o);
            fbl[ks][j] = *(const f16x8*)(BgL + o);
        }
    }
    __syncthreads();

    f32x4 acc[2][2] = {};
#pragma unroll
    for (int win = 0; win < 8; win++) {
        f16* AhC = (win & 1) ? Ah1 : Ah0;
        f16* AlC = (win & 1) ? Al1 : Al0;
        f16* AhN = (win & 1) ? Ah0 : Ah1;
        f16* AlN = (win & 1) ? Al0 : Al1;

        float va[8];
        if (win < 7) {
            int k = (win + 1) * 64 + akoct * 8;
            const float* p = (k < 256)
                ? msgP + ((size_t)l * GG + g0 + arow) * HH + k
                : hidCd + (size_t)(g0 + arow) * HH + (k - 256);
            float4 v0 = *(const float4*)p, v1 = *(const float4*)(p + 4);
            va[0]=v0.x; va[1]=v0.y; va[2]=v0.z; va[3]=v0.w;
            va[4]=v1.x; va[5]=v1.y; va[6]=v1.z; va[7]=v1.w;
        }
        f16x8 nbh[2][2], nbl[2][2];
        if (win < 7) {
#pragma unroll
            for (int ks = 0; ks < 2; ks++) {
                size_t kbase = (size_t)(d * 16 + (win + 1) * 2 + ks) * 1024;
#pragma unroll
                for (int j = 0; j < 2; j++) {
                    size_t o = (kbase + (c * 128 + wc * 32 + j * 16 + lr)) * 32 + lh * 8;
                    nbh[ks][j] = *(const f16x8*)(BgH + o);
                    nbl[ks][j] = *(const f16x8*)(BgL + o);
                }
            }
        }
#pragma unroll
        for (int ks = 0; ks < 2; ks++) {
            f16x8 fah[2], fal[2];
#pragma unroll
            for (int i = 0; i < 2; i++) {
                fah[i] = *(const f16x8*)&AhC[(wg * 32 + i * 16 + lr) * 72 + ks * 32 + lh * 8];
                fal[i] = *(const f16x8*)&AlC[(wg * 32 + i * 16 + lr) * 72 + ks * 32 + lh * 8];
            }
#pragma unroll
            for (int j = 0; j < 2; j++) {
#pragma unroll
                for (int i = 0; i < 2; i++) {
                    acc[i][j] = MFMA16(fah[i], fbh[ks][j], acc[i][j]);
                    acc[i][j] = MFMA16(fah[i], fbl[ks][j], acc[i][j]);
                    acc[i][j] = MFMA16(fal[i], fbh[ks][j], acc[i][j]);
                }
            }
        }
        if (win < 7) {
            f16x8 hi, lo;
#pragma unroll
            for (int e = 0; e < 8; e++) {
                float a = va[e] * myS;
                f16 h = (f16)a;
                hi[e] = h;
                lo[e] = (f16)(a - (float)h);
            }
            *(f16x8*)&AhN[arow * 72 + akoct * 8] = hi;
            *(f16x8*)&AlN[arow * 72 + akoct * 8] = lo;
#pragma unroll
            for (int ks = 0; ks < 2; ks++)
#pragma unroll
                for (int j = 0; j < 2; j++) {
                    fbh[ks][j] = nbh[ks][j];
                    fbl[ks][j] = nbl[ks][j];
                }
        }
        __syncthreads();
    }

#pragma unroll
    for (int i = 0; i < 2; i++) {
#pragma unroll
        for (int e = 0; e < 4; e++) {
            int ml = wg * 32 + i * 16 + lh * 4 + e;
            float inv = DSB / scL[ml];
#pragma unroll
            for (int j = 0; j < 2; j++)
                Cs[ml * 132 + wc * 32 + j * 16 + lr] = acc[i][j][e] * inv;
        }
    }
    __syncthreads();

    const float* b4 = bias4 + d * 1024;
    const int jl = tid & 31;
    const int J  = c * 32 + jl;
    const int gbase = (tid >> 5) * 4;
    const float bb0 = b4[4 * J + 0], bb1 = b4[4 * J + 1];
    const float bb2 = b4[4 * J + 2], bb3 = b4[4 * J + 3];
    float* o = d ? outB : outF;
#pragma unroll
    for (int i = 0; i < 4; i++) {
        int gl = gbase + i;
        int g = g0 + gl;
        f32x4 gv = *(const f32x4*)&Cs[gl * 132 + jl * 4];
        float r = 1.f / (1.f + expf(-(gv[0] + bb0)));
        float z = 1.f / (1.f + expf(-(gv[1] + bb1)));
        float nn = tanhf(gv[2] + bb2 + r * (gv[3] + bb3));
        float hp = hidCd[(size_t)g * HH + J];
        float hnew = (1.f - z) * nn + z * hp;
        hidNd[(size_t)g * HH + J] = hnew;
        if (l < gcnt[g]) o[(size_t)(starts[g] + l) * HH + J] = hnew;
    }
}

__global__ void fill_sentinel(float* __restrict__ out, float v)
{
    size_t idx = (size_t)blockIdx.x * 256 + threadIdx.x;
    out[idx] = v;
}

// ---------------------------------------------------------------------------
// Workspace layout identical to round 3-10 (verified).
// ---------------------------------------------------------------------------
extern "C" void kernel_launch(void* const* d_in, const int* in_sizes, int n_in,
                              void* d_out, int out_size, void* d_ws, size_t ws_size,
                              hipStream_t stream)
{
    (void)in_sizes; (void)n_in; (void)out_size;
    const float* x         = (const float*)d_in[0];
    const float* edge_attr = (const float*)d_in[1];
    const int*   eidx      = (const int*)d_in[2];
    const int*   batch     = (const int*)d_in[3];
    const float* w_atom    = (const float*)d_in[4];
    const float* b_atom    = (const float*)d_in[5];
    const float* w_bond    = (const float*)d_in[6];
    const float* b_bond    = (const float*)d_in[7];
    const float* conv_w    = (const float*)d_in[8];
    const float* conv_b    = (const float*)d_in[9];
    const float* w_lin     = (const float*)d_in[10];
    const float* b_lin     = (const float*)d_in[11];
    const float* gru_bias  = (const float*)d_in[12];
    const float* w_ih      = (const float*)d_in[13];
    const float* w_hh      = (const float*)d_in[14];
    const float* b_ih      = (const float*)d_in[15];
    const float* b_hh      = (const float*)d_in[16];
    const float* w_out     = (const float*)d_in[17];
    const float* b_out     = (const float*)d_in[18];

    const int* row = eidx;
    const int* col = eidx + NEDGES;

    const size_t NH = (size_t)NNODES * HH;

    float* W   = (float*)d_ws;
    float* W0  = W;
    float* W1  = W + NH;
    float* W1h = W + 2 * NH;
    float* W2  = W + 3 * NH;
    float* DO  = (float*)d_out;

    size_t off = 4 * NH;
    int* counts  = (int*)(W + off);      off += NNODES;
    int* cursor  = (int*)(W + off);      off += NNODES;
    int* gcnt    = (int*)(W + off);      off += GG;
    int* starts  = (int*)(W + off);      off += GG;
    int* offsets = (int*)(W + off);      off += NNODES + 1;
    int* elist   = (int*)(W + off);      off += NEDGES;
    float* scX    = W + off;             off += NNODES;
    float* scEA   = W + off;             off += NEDGES;
    float* scHbA  = W + off;             off += NEDGES;
    float* scHbB  = W + off;             off += NEDGES;
    float* scAtom = W + off;             off += NNODES;
    float* scAggr = W + off;             off += NNODES;
    float* scXp   = W + off;             off += NNODES;
    float* scGru  = W + off;             off += GG;
    off = (off + 3) & ~(size_t)3;
    f16* fp = (f16*)(W + off);
    f16* watomH = fp;                     fp += 4 * 256 * 32;
    f16* watomL = fp;                     fp += 4 * 256 * 32;
    f16* wbondH = fp;                     fp += 2 * 256 * 32;
    f16* wbondL = fp;                     fp += 2 * 256 * 32;
    f16* convH[3]; f16* convL[3];
    for (int i = 0; i < 3; i++) { convH[i] = fp; fp += 8 * 256 * 32; convL[i] = fp; fp += 8 * 256 * 32; }
    f16* wlinH = fp;                      fp += 24 * 256 * 32;
    f16* wlinL = fp;                      fp += 24 * 256 * 32;
    f16* woutH = fp;                      fp += 16 * 256 * 32;
    f16* woutL = fp;                      fp += 16 * 256 * 32;

    const size_t NEED = (char*)fp - (char*)d_ws;
    if (ws_size < NEED) {
        fill_sentinel<<<(int)(NH / 256), 256, 0, stream>>>((float*)d_out, (float)ws_size);
        return;
    }

    // d_out overlay (dead between final booster and final GEMM)
    float* hid0  = DO;
    float* hid1  = DO + 2 * (size_t)GG * HH;
    float* bias4 = DO + 4 * (size_t)GG * HH;
    f16* BgH = (f16*)(bias4 + 2048);
    f16* BgL = BgH + (size_t)2 * 16 * 1024 * 32;

    hipMemsetAsync(counts, 0, (size_t)(2 * NNODES + 2 * GG) * sizeof(int), stream);
    prep_graphs<<<(NNODES + 255) / 256, 256, 0, stream>>>(batch, starts, gcnt);
    csr_count<<<(NEDGES + 255) / 256, 256, 0, stream>>>(row, counts);
    scan_offsets<<<1, 1024, 0, stream>>>(counts, offsets);
    csr_fill<<<(NEDGES + 255) / 256, 256, 0, stream>>>(row, offsets, cursor, elist);

    rowscale<<<NNODES, 64, 0, stream>>>(x, 128, scX);
    rowscale<<<NEDGES, 64, 0, stream>>>(edge_attr, 64, scEA);

    prep_wT_all<<<2240, 256, 0, stream>>>(w_atom, w_bond, conv_w, w_lin, w_out,
        watomH, watomL, wbondH, wbondL, convH[0], convL[0], convH[1], convL[1],
        convH[2], convL[2], wlinH, wlinL, woutH, woutL);

    // x_proj = relu(x @ w_atom + b_atom) -> W0, scAtom
    gemm_f16x3<0, true, false, true, 3><<<NNODES / 64, 256, 0, stream>>>(
        x, nullptr, nullptr, nullptr, nullptr, nullptr, watomH, watomL, b_atom,
        scX, nullptr, nullptr, W0, nullptr, scAtom, 128);
    // bondA = relu(edge_attr @ w_bond + b_bond) -> (W1, W1h), scHbA
    gemm_f16x3<0, true, true, true, 3><<<NEDGES / 64, 256, 0, stream>>>(
        edge_attr, nullptr, nullptr, nullptr, nullptr, nullptr, wbondH, wbondL, b_bond,
        scEA, nullptr, nullptr, W1, W1h, scHbA, 64);

    float* cur_lo = W1; float* cur_hi = W1h; float* cur_sc = scHbA;
    float* nxt_lo = W2; float* nxt_hi = DO;  float* nxt_sc = scHbB;
    for (int i = 0; i < 3; i++) {
        booster<<<NNODES / 4, 256, 0, stream>>>(cur_lo, cur_hi, W0, W0, offsets, elist, scAtom);
        gemm_f16x3<1, true, true, true, 3><<<NEDGES / 64, 256, 0, stream>>>(
            nullptr, W0, cur_lo, nullptr, row, col, convH[i], convL[i],
            conv_b + (size_t)i * HH, scAtom, cur_sc, nullptr, nxt_lo, nxt_hi, nxt_sc, 256);
        float* t0 = cur_lo; cur_lo = nxt_lo; nxt_lo = t0;
        float* t1 = cur_hi; cur_hi = nxt_hi; nxt_hi = t1;
        float* t2 = cur_sc; cur_sc = nxt_sc; nxt_sc = t2;
    }
    // aggr = h_atom + booster(bondB) -> W1 (bondA dead)
    booster<<<NNODES / 4, 256, 0, stream>>>(cur_lo, cur_hi, W0, W1, offsets, elist, scAggr);
    // recompute x_proj -> W1h
    gemm_f16x3<0, true, false, true, 3><<<NNODES / 64, 256, 0, stream>>>(
        x, nullptr, nullptr, nullptr, nullptr, nullptr, watomH, watomL, b_atom,
        scX, nullptr, nullptr, W1h, nullptr, scXp, 128);
    // h = concat(aggr, h_atom, x_proj) @ w_lin + b_lin -> W2
    gemm_f16x3<2, false, false, false, 3><<<NNODES / 64, 256, 0, stream>>>(
        nullptr, W1, W0, W1h, nullptr, nullptr, wlinH, wlinL, b_lin,
        scAggr, scAtom, scXp, W2, nullptr, nullptr, 768);

    // GRU prep (DO bond rows dead now)
    h0_init<<<GG / 4, 256, 0, stream>>>(W2, starts, gcnt, hid0, scGru);
    build_msgP<<<dim3(LL, GG), 256, 0, stream>>>(W2, gru_bias, starts, gcnt, W1h);
    prep_gruW<<<(2 * 512 * 1024) / 256, 256, 0, stream>>>(w_ih, w_hh, b_ih, b_hh, BgH, BgL, bias4);

    for (int t = 0; t < LL; t++) {
        float* hc = (t & 1) ? hid1 : hid0;
        float* hx = (t & 1) ? hid0 : hid1;
        gru_step_f16<<<256, 512, 0, stream>>>(W1h, BgH, BgL, bias4, hc, hx,
                                              scGru, starts, gcnt, W0, W1, t);
    }

    // out = relu(concat(outF, outB) @ w_out + b_out), pure f16 (NX=1)
    gemm_f16x3<3, true, false, false, 1><<<NNODES / 64, 256, 0, stream>>>(
        nullptr, W0, W1, nullptr, nullptr, batch, woutH, nullptr, b_out,
        scGru, nullptr, nullptr, (float*)d_out, nullptr, nullptr, 512);
}